// Round 5
// baseline (338.880 us; speedup 1.0000x reference)
//
#include <hip/hip_runtime.h>
#include <hip/hip_bf16.h>
#include <math.h>

#define T0 128
#define BN 256           // B*N = 8*32
#define Ff 128
#define Hh 256
#define NODE0 32768      // BN*T0
#define E0 262144        // NODE0*8
#define T1 64
#define NODE1 16384      // BN*T1
#define E1 131072
#define CAP 48           // per-node in-edge capacity; deg ~ Poisson(8), P(>48) ~ 1e-25

typedef __attribute__((ext_vector_type(8))) short bhalf8;
typedef __attribute__((ext_vector_type(4))) float floatx4;

__device__ __forceinline__ unsigned short f2bf(float x) {
  union { float f; unsigned u; } v; v.f = x;
  unsigned r = v.u + 0x7fff + ((v.u >> 16) & 1);
  return (unsigned short)(r >> 16);
}
__device__ __forceinline__ float bf2f(unsigned short b) {
  union { unsigned u; float f; } v; v.u = ((unsigned)b) << 16;
  return v.f;
}

// ---------------- fused prep kernel ----------------
// blocks [0,2048): data fp32 [T][BN][F] -> X0b bf16 [bn*T+t][F]
// blocks [2048,2176): W0 -> Wbot0/Wd0 ; [2176,2432): W1 -> Wbot1/Wd1
// blocks [2432,3712): Wc0 -> Wtb0 ; [3712,4992): Wc1 -> Wtb1
__global__ void k_prep(const float* __restrict__ data, unsigned short* __restrict__ X0b,
                       const float* __restrict__ W0, unsigned short* __restrict__ Wbot0,
                       unsigned short* __restrict__ Wd0,
                       const float* __restrict__ W1, unsigned short* __restrict__ Wbot1,
                       unsigned short* __restrict__ Wd1,
                       const float* __restrict__ Wc0, unsigned short* __restrict__ Wtb0,
                       const float* __restrict__ Wc1, unsigned short* __restrict__ Wtb1) {
  int b = blockIdx.x;
  int tid = threadIdx.x;
  if (b < 2048) {
    int idx = b * 256 + tid;          // NODE0*16, 8 elems each
    int c8 = idx & 15;
    int r  = idx >> 4;
    int t  = r & (T0 - 1);
    int bn = r >> 7;
    const float* s = data + ((size_t)t * BN + bn) * Ff + c8 * 8;
    float4 a = *(const float4*)s;
    float4 bb = *(const float4*)(s + 4);
    unsigned short o[8];
    o[0] = f2bf(a.x); o[1] = f2bf(a.y); o[2] = f2bf(a.z); o[3] = f2bf(a.w);
    o[4] = f2bf(bb.x); o[5] = f2bf(bb.y); o[6] = f2bf(bb.z); o[7] = f2bf(bb.w);
    *(int4*)(X0b + ((size_t)(bn * T0 + t) * Ff + c8 * 8)) = *(int4*)o;
  } else if (b < 2176) {
    int idx = (b - 2048) * 256 + tid; // 32768 = 256*128
    int n = idx >> 7, k = idx & 127;
    float top = W0[(size_t)k * 256 + n];
    float bot = W0[(size_t)(128 + k) * 256 + n];
    Wbot0[idx] = f2bf(bot);
    Wd0[idx]   = f2bf(top - bot);
  } else if (b < 2432) {
    int idx = (b - 2176) * 256 + tid; // 65536 = 256*256
    int n = idx >> 8, k = idx & 255;
    float top = W1[(size_t)k * 256 + n];
    float bot = W1[(size_t)(256 + k) * 256 + n];
    Wbot1[idx] = f2bf(bot);
    Wd1[idx]   = f2bf(top - bot);
  } else if (b < 3712) {
    int idx = (b - 2432) * 256 + tid; // 5*65536
    int tap = idx >> 16, o = (idx >> 8) & 255, i = idx & 255;
    Wtb0[idx] = f2bf(Wc0[((size_t)o * 256 + i) * 5 + tap]);
  } else {
    int idx = (b - 3712) * 256 + tid;
    int tap = idx >> 16, o = (idx >> 8) & 255, i = idx & 255;
    Wtb1[idx] = f2bf(Wc1[((size_t)o * 256 + i) * 5 + tap]);
  }
}

// ---------------- bucketed edge fill ----------------

__global__ void k_fill(const int* __restrict__ srcIdx, const int* __restrict__ dstIdx,
                       int* __restrict__ cnt, int* __restrict__ slot, int E) {
  int e = blockIdx.x * 256 + threadIdx.x;
  if (e < E) {
    int d = dstIdx[e];
    int p = atomicAdd(&cnt[d], 1);
    if (p < CAP) slot[(size_t)d * CAP + p] = srcIdx[e];
  }
}

// per-node segment max over bf16 rows of Bm [*,256]; writes Mm bf16.
// Empty segments stay -inf (bf16 0xFF80): gemm<1>'s relu then yields 0,
// exactly matching PyG's isneginf->0 fill.
__global__ __launch_bounds__(256) void k_maxg(const unsigned short* __restrict__ Bm,
                                              const int* __restrict__ cnt,
                                              const int* __restrict__ slot,
                                              unsigned short* __restrict__ Mm) {
  int node = blockIdx.x * 4 + (threadIdx.x >> 6);
  int lane = threadIdx.x & 63;
  int n = cnt[node];
  if (n > CAP) n = CAP;
  const int* sl = slot + (size_t)node * CAP;
  float4 m = make_float4(-INFINITY, -INFINITY, -INFINITY, -INFINITY);
  int i = 0;
  for (; i + 4 <= n; i += 4) {
    int s0 = sl[i], s1 = sl[i + 1], s2 = sl[i + 2], s3 = sl[i + 3];
    ushort4 v0 = *(const ushort4*)(Bm + (size_t)s0 * 256 + lane * 4);
    ushort4 v1 = *(const ushort4*)(Bm + (size_t)s1 * 256 + lane * 4);
    ushort4 v2 = *(const ushort4*)(Bm + (size_t)s2 * 256 + lane * 4);
    ushort4 v3 = *(const ushort4*)(Bm + (size_t)s3 * 256 + lane * 4);
    m.x = fmaxf(fmaxf(fmaxf(m.x, bf2f(v0.x)), fmaxf(bf2f(v1.x), bf2f(v2.x))), bf2f(v3.x));
    m.y = fmaxf(fmaxf(fmaxf(m.y, bf2f(v0.y)), fmaxf(bf2f(v1.y), bf2f(v2.y))), bf2f(v3.y));
    m.z = fmaxf(fmaxf(fmaxf(m.z, bf2f(v0.z)), fmaxf(bf2f(v1.z), bf2f(v2.z))), bf2f(v3.z));
    m.w = fmaxf(fmaxf(fmaxf(m.w, bf2f(v0.w)), fmaxf(bf2f(v1.w), bf2f(v2.w))), bf2f(v3.w));
  }
  for (; i < n; ++i) {
    int s = sl[i];
    ushort4 v = *(const ushort4*)(Bm + (size_t)s * 256 + lane * 4);
    m.x = fmaxf(m.x, bf2f(v.x));
    m.y = fmaxf(m.y, bf2f(v.y));
    m.z = fmaxf(m.z, bf2f(v.z));
    m.w = fmaxf(m.w, bf2f(v.w));
  }
  ushort4 o;
  o.x = f2bf(m.x); o.y = f2bf(m.y); o.z = f2bf(m.z); o.w = f2bf(m.w);
  *(ushort4*)(Mm + (size_t)node * 256 + lane * 4) = o;
}

// ---------------- MFMA GEMM (register-prefetch pipelined) ----------------
// C[M][256] = A[M][K](bf16) @ Wb^T, Wb [256][K] bf16 (n-major, k-contig)
// MODE 0: C = acc. MODE 1: C = relu(acc + bias + Mm).
template <int MODE>
__global__ __launch_bounds__(256) void k_gemm(const unsigned short* __restrict__ A,
                                              const unsigned short* __restrict__ Wb,
                                              unsigned short* __restrict__ C, int K,
                                              const float* __restrict__ bias,
                                              const unsigned short* __restrict__ Mm) {
  __shared__ __align__(16) short A_lds[128 * 72];
  __shared__ __align__(16) short B_lds[128 * 72];
  int tid = threadIdx.x;
  int row0 = blockIdx.x * 128;
  int col0 = blockIdx.y * 128;
  int lane = tid & 63, wv = tid >> 6;
  int m16 = lane & 15, quad = lane >> 4;
  int sr = tid >> 3, sseg = tid & 7;          // staging row/seg base (tid -> 32 rows x 8 segs)

  int4 Ar[4], Br[4];
#pragma unroll
  for (int i = 0; i < 4; ++i) {
    int r = sr + i * 32;
    Ar[i] = *(const int4*)(A + (size_t)(row0 + r) * K + sseg * 8);
    Br[i] = *(const int4*)(Wb + (size_t)(col0 + r) * K + sseg * 8);
  }
#pragma unroll
  for (int i = 0; i < 4; ++i) {
    int r = sr + i * 32;
    *(int4*)&A_lds[r * 72 + sseg * 8] = Ar[i];
    *(int4*)&B_lds[r * 72 + sseg * 8] = Br[i];
  }
  __syncthreads();

  floatx4 acc[2][8];
#pragma unroll
  for (int mt = 0; mt < 2; ++mt)
#pragma unroll
    for (int nt = 0; nt < 8; ++nt) acc[mt][nt] = (floatx4){0.f, 0.f, 0.f, 0.f};

  int NKB = K >> 6;
  for (int s = 0; s < NKB; ++s) {
    if (s + 1 < NKB) {
      int kb = (s + 1) << 6;
#pragma unroll
      for (int i = 0; i < 4; ++i) {
        int r = sr + i * 32;
        Ar[i] = *(const int4*)(A + (size_t)(row0 + r) * K + kb + sseg * 8);
        Br[i] = *(const int4*)(Wb + (size_t)(col0 + r) * K + kb + sseg * 8);
      }
    }
#pragma unroll
    for (int ks = 0; ks < 2; ++ks) {
      bhalf8 a[2];
#pragma unroll
      for (int mt = 0; mt < 2; ++mt)
        a[mt] = *(const bhalf8*)&A_lds[(wv * 32 + mt * 16 + m16) * 72 + ks * 32 + quad * 8];
#pragma unroll
      for (int nt = 0; nt < 8; ++nt) {
        bhalf8 b = *(const bhalf8*)&B_lds[(nt * 16 + m16) * 72 + ks * 32 + quad * 8];
#pragma unroll
        for (int mt = 0; mt < 2; ++mt)
          acc[mt][nt] = __builtin_amdgcn_mfma_f32_16x16x32_bf16(a[mt], b, acc[mt][nt], 0, 0, 0);
      }
    }
    if (s + 1 < NKB) {
      __syncthreads();
#pragma unroll
      for (int i = 0; i < 4; ++i) {
        int r = sr + i * 32;
        *(int4*)&A_lds[r * 72 + sseg * 8] = Ar[i];
        *(int4*)&B_lds[r * 72 + sseg * 8] = Br[i];
      }
      __syncthreads();
    }
  }

#pragma unroll
  for (int mt = 0; mt < 2; ++mt) {
    int g0 = row0 + wv * 32 + mt * 16 + quad * 4;
#pragma unroll
    for (int nt = 0; nt < 8; ++nt) {
      int c = col0 + nt * 16 + m16;
      float bv = (MODE == 1) ? bias[c] : 0.f;
#pragma unroll
      for (int r = 0; r < 4; ++r) {
        float v = acc[mt][nt][r];
        if (MODE == 1) v = fmaxf(v + bv + bf2f(Mm[(size_t)(g0 + r) * 256 + c]), 0.f);
        C[(size_t)(g0 + r) * 256 + c] = f2bf(v);
      }
    }
  }
}

// ---------------- MFMA temporal conv (register-prefetch pipelined) ----------------
// Y = maxpool2(relu(conv1d(X, Wtb, k=5, pad=2) + bc)); X bf16 [M][256] as [BN][TR][256]
// One block per (bn, col-half). A pad rows zeroed once; per step prefetch next B
// (and next A at kb boundary) into regs during MFMA, LDS handoff after barrier.
template <int TR, bool OUT_F32>
__global__ __launch_bounds__(256) void k_conv(const unsigned short* __restrict__ X,
                                              const unsigned short* __restrict__ Wtb,
                                              const float* __restrict__ bc,
                                              void* __restrict__ Yout) {
  const int MT = TR / 64;
  const int AN = TR / 32;                    // A int4s per thread
  const int NS = 20;                         // 4 kb-chunks x 5 taps
  __shared__ __align__(16) short A_lds[(TR + 4) * 72];
  __shared__ __align__(16) short B_lds[128 * 72];
  int tid = threadIdx.x;
  int row0 = blockIdx.x * TR;                // one bn per block
  int col0 = blockIdx.y * 128;
  int lane = tid & 63, wv = tid >> 6;
  int m16 = lane & 15, quad = lane >> 4;
  int sr = tid >> 3, sseg = tid & 7;         // staging: 32 rows x 8 segs per 256 thr

  // zero the 4 pad rows (rows 0,1,TR+2,TR+3) once — zero in every kb chunk
  if (tid < 32) {
    int r = tid >> 3;
    int rr = (r < 2) ? r : (TR + r);
    *(int4*)&A_lds[rr * 72 + (tid & 7) * 8] = (int4){0, 0, 0, 0};
  }

  int4 Ar[AN], Br[4];
#pragma unroll
  for (int i = 0; i < AN; ++i)
    Ar[i] = *(const int4*)(X + (size_t)(row0 + sr + i * 32) * 256 + sseg * 8);
#pragma unroll
  for (int i = 0; i < 4; ++i)
    Br[i] = *(const int4*)(Wtb + (size_t)(col0 + sr + i * 32) * 256 + sseg * 8);
#pragma unroll
  for (int i = 0; i < AN; ++i)
    *(int4*)&A_lds[(sr + i * 32 + 2) * 72 + sseg * 8] = Ar[i];
#pragma unroll
  for (int i = 0; i < 4; ++i)
    *(int4*)&B_lds[(sr + i * 32) * 72 + sseg * 8] = Br[i];
  __syncthreads();

  floatx4 acc[MT][8];
#pragma unroll
  for (int mt = 0; mt < MT; ++mt)
#pragma unroll
    for (int nt = 0; nt < 8; ++nt) acc[mt][nt] = (floatx4){0.f, 0.f, 0.f, 0.f};

#pragma unroll 5
  for (int s = 0; s < NS; ++s) {
    int sn = s + 1;
    int tap_n = sn % 5;
    int kb_n = (sn / 5) << 6;
    bool hn = sn < NS;
    if (hn) {
#pragma unroll
      for (int i = 0; i < 4; ++i)
        Br[i] = *(const int4*)(Wtb + (size_t)tap_n * 65536 +
                               (size_t)(col0 + sr + i * 32) * 256 + kb_n + sseg * 8);
      if (tap_n == 0) {
#pragma unroll
        for (int i = 0; i < AN; ++i)
          Ar[i] = *(const int4*)(X + (size_t)(row0 + sr + i * 32) * 256 + kb_n + sseg * 8);
      }
    }
    int tap = s % 5;
#pragma unroll
    for (int ks = 0; ks < 2; ++ks) {
      bhalf8 a[MT];
#pragma unroll
      for (int mt = 0; mt < MT; ++mt)
        a[mt] = *(const bhalf8*)&A_lds[(wv * (16 * MT) + mt * 16 + m16 + tap) * 72 +
                                       ks * 32 + quad * 8];
#pragma unroll
      for (int nt = 0; nt < 8; ++nt) {
        bhalf8 b = *(const bhalf8*)&B_lds[(nt * 16 + m16) * 72 + ks * 32 + quad * 8];
#pragma unroll
        for (int mt = 0; mt < MT; ++mt)
          acc[mt][nt] = __builtin_amdgcn_mfma_f32_16x16x32_bf16(a[mt], b, acc[mt][nt], 0, 0, 0);
      }
    }
    if (hn) {
      __syncthreads();
#pragma unroll
      for (int i = 0; i < 4; ++i)
        *(int4*)&B_lds[(sr + i * 32) * 72 + sseg * 8] = Br[i];
      if (tap_n == 0) {
#pragma unroll
        for (int i = 0; i < AN; ++i)
          *(int4*)&A_lds[(sr + i * 32 + 2) * 72 + sseg * 8] = Ar[i];
      }
      __syncthreads();
    }
  }

#pragma unroll
  for (int mt = 0; mt < MT; ++mt) {
    int gbase = row0 + wv * (16 * MT) + mt * 16 + quad * 4;
#pragma unroll
    for (int nt = 0; nt < 8; ++nt) {
      int c = col0 + nt * 16 + m16;
      float bv = bc[c];
      float y0 = fmaxf(acc[mt][nt][0] + bv, 0.f);
      float y1 = fmaxf(acc[mt][nt][1] + bv, 0.f);
      float y2 = fmaxf(acc[mt][nt][2] + bv, 0.f);
      float y3 = fmaxf(acc[mt][nt][3] + bv, 0.f);
      float p0 = fmaxf(y0, y1);
      float p1 = fmaxf(y2, y3);
      int o0 = gbase >> 1;
      if (OUT_F32) {
        float* Y = (float*)Yout;
        Y[(size_t)o0 * 256 + c] = p0;
        Y[(size_t)(o0 + 1) * 256 + c] = p1;
      } else {
        unsigned short* Y = (unsigned short*)Yout;
        Y[(size_t)o0 * 256 + c] = f2bf(p0);
        Y[(size_t)(o0 + 1) * 256 + c] = f2bf(p1);
      }
    }
  }
}

extern "C" void kernel_launch(void* const* d_in, const int* in_sizes, int n_in,
                              void* d_out, int out_size, void* d_ws, size_t ws_size,
                              hipStream_t stream) {
  const float* data = (const float*)d_in[0];
  const int* ei0 = (const int*)d_in[2];
  const int* ei1 = (const int*)d_in[3];
  const float* W0  = (const float*)d_in[4];
  const float* b0  = (const float*)d_in[5];
  const float* Wc0 = (const float*)d_in[6];
  const float* bc0 = (const float*)d_in[7];
  const float* W1  = (const float*)d_in[8];
  const float* b1  = (const float*)d_in[9];
  const float* Wc1 = (const float*)d_in[10];
  const float* bc1 = (const float*)d_in[11];
  float* out = (float*)d_out;

  char* base = (char*)d_ws;
  size_t off = 0;
  auto alloc = [&](size_t bytes) { void* p = base + off; off += (bytes + 255) & ~(size_t)255; return p; };
  unsigned short* X0b   = (unsigned short*)alloc((size_t)NODE0 * Ff * 2);
  unsigned short* Bm    = (unsigned short*)alloc((size_t)NODE0 * Hh * 2);
  unsigned short* Mm    = (unsigned short*)alloc((size_t)NODE0 * Hh * 2);
  unsigned short* X1b   = (unsigned short*)alloc((size_t)NODE0 * Hh * 2);
  unsigned short* Y0b   = (unsigned short*)alloc((size_t)NODE1 * Hh * 2);
  unsigned short* Wbot0 = (unsigned short*)alloc(256 * 128 * 2);
  unsigned short* Wd0   = (unsigned short*)alloc(256 * 128 * 2);
  unsigned short* Wbot1 = (unsigned short*)alloc(256 * 256 * 2);
  unsigned short* Wd1   = (unsigned short*)alloc(256 * 256 * 2);
  unsigned short* Wtb0  = (unsigned short*)alloc(5 * 65536 * 2);
  unsigned short* Wtb1  = (unsigned short*)alloc(5 * 65536 * 2);
  int* cnt0  = (int*)alloc(NODE0 * 4);      // cnt0+cnt1 adjacent: one memset
  int* cnt1  = (int*)alloc(NODE1 * 4);
  int* slot0 = (int*)alloc((size_t)NODE0 * CAP * 4);
  int* slot1 = (int*)alloc((size_t)NODE1 * CAP * 4);
  (void)cnt1;

  hipMemsetAsync(cnt0, 0, (NODE0 + NODE1) * sizeof(int), stream);

  k_prep<<<4992, 256, 0, stream>>>(data, X0b, W0, Wbot0, Wd0, W1, Wbot1, Wd1,
                                   Wc0, Wtb0, Wc1, Wtb1);

  // ---- layer 0 ----
  k_fill<<<E0 / 256, 256, 0, stream>>>(ei0, ei0 + E0, cnt0, slot0, E0);
  k_gemm<0><<<dim3(NODE0 / 128, 2), 256, 0, stream>>>(X0b, Wbot0, Bm, 128, nullptr, nullptr);
  k_maxg<<<NODE0 / 4, 256, 0, stream>>>(Bm, cnt0, slot0, Mm);
  k_gemm<1><<<dim3(NODE0 / 128, 2), 256, 0, stream>>>(X0b, Wd0, X1b, 128, b0, Mm);
  k_conv<128, false><<<dim3(BN, 2), 256, 0, stream>>>(X1b, Wtb0, bc0, Y0b);

  // ---- layer 1 ----
  k_fill<<<E1 / 256, 256, 0, stream>>>(ei1, ei1 + E1, cnt1, slot1, E1);
  k_gemm<0><<<dim3(NODE1 / 128, 2), 256, 0, stream>>>(Y0b, Wbot1, Bm, 256, nullptr, nullptr);
  k_maxg<<<NODE1 / 4, 256, 0, stream>>>(Bm, cnt1, slot1, Mm);
  k_gemm<1><<<dim3(NODE1 / 128, 2), 256, 0, stream>>>(Y0b, Wd1, X1b, 256, b1, Mm);
  k_conv<64, true><<<dim3(BN, 2), 256, 0, stream>>>(X1b, Wtb1, bc1, out);
}

// Round 6
// 258.507 us; speedup vs baseline: 1.3109x; 1.3109x over previous
//
#include <hip/hip_runtime.h>
#include <hip/hip_bf16.h>
#include <math.h>

#define T0 128
#define BN 256           // B*N = 8*32
#define Ff 128
#define Hh 256
#define NODE0 32768      // BN*T0
#define E0 262144        // NODE0*8
#define T1 64
#define NODE1 16384      // BN*T1
#define E1 131072
#define CAP 48           // per-node in-edge capacity; deg ~ Poisson(8), P(>48) ~ 1e-25

typedef __attribute__((ext_vector_type(8))) short bhalf8;
typedef __attribute__((ext_vector_type(4))) float floatx4;

__device__ __forceinline__ unsigned short f2bf(float x) {
  union { float f; unsigned u; } v; v.f = x;
  unsigned r = v.u + 0x7fff + ((v.u >> 16) & 1);
  return (unsigned short)(r >> 16);
}
__device__ __forceinline__ float bf2f(unsigned short b) {
  union { unsigned u; float f; } v; v.u = ((unsigned)b) << 16;
  return v.f;
}

// ---------------- fused prep kernel ----------------
// blocks [0,2048): data fp32 [T][BN][F] -> X0b bf16 [bn*T+t][F]
// blocks [2048,2176): W0 -> Wbot0/Wd0 ; [2176,2432): W1 -> Wbot1/Wd1
// blocks [2432,3712): Wc0 -> Wtb0 ; [3712,4992): Wc1 -> Wtb1
__global__ void k_prep(const float* __restrict__ data, unsigned short* __restrict__ X0b,
                       const float* __restrict__ W0, unsigned short* __restrict__ Wbot0,
                       unsigned short* __restrict__ Wd0,
                       const float* __restrict__ W1, unsigned short* __restrict__ Wbot1,
                       unsigned short* __restrict__ Wd1,
                       const float* __restrict__ Wc0, unsigned short* __restrict__ Wtb0,
                       const float* __restrict__ Wc1, unsigned short* __restrict__ Wtb1) {
  int b = blockIdx.x;
  int tid = threadIdx.x;
  if (b < 2048) {
    int idx = b * 256 + tid;          // NODE0*16, 8 elems each
    int c8 = idx & 15;
    int r  = idx >> 4;
    int t  = r & (T0 - 1);
    int bn = r >> 7;
    const float* s = data + ((size_t)t * BN + bn) * Ff + c8 * 8;
    float4 a = *(const float4*)s;
    float4 bb = *(const float4*)(s + 4);
    unsigned short o[8];
    o[0] = f2bf(a.x); o[1] = f2bf(a.y); o[2] = f2bf(a.z); o[3] = f2bf(a.w);
    o[4] = f2bf(bb.x); o[5] = f2bf(bb.y); o[6] = f2bf(bb.z); o[7] = f2bf(bb.w);
    *(int4*)(X0b + ((size_t)(bn * T0 + t) * Ff + c8 * 8)) = *(int4*)o;
  } else if (b < 2176) {
    int idx = (b - 2048) * 256 + tid; // 32768 = 256*128
    int n = idx >> 7, k = idx & 127;
    float top = W0[(size_t)k * 256 + n];
    float bot = W0[(size_t)(128 + k) * 256 + n];
    Wbot0[idx] = f2bf(bot);
    Wd0[idx]   = f2bf(top - bot);
  } else if (b < 2432) {
    int idx = (b - 2176) * 256 + tid; // 65536 = 256*256
    int n = idx >> 8, k = idx & 255;
    float top = W1[(size_t)k * 256 + n];
    float bot = W1[(size_t)(256 + k) * 256 + n];
    Wbot1[idx] = f2bf(bot);
    Wd1[idx]   = f2bf(top - bot);
  } else if (b < 3712) {
    int idx = (b - 2432) * 256 + tid; // 5*65536
    int tap = idx >> 16, o = (idx >> 8) & 255, i = idx & 255;
    Wtb0[idx] = f2bf(Wc0[((size_t)o * 256 + i) * 5 + tap]);
  } else {
    int idx = (b - 3712) * 256 + tid;
    int tap = idx >> 16, o = (idx >> 8) & 255, i = idx & 255;
    Wtb1[idx] = f2bf(Wc1[((size_t)o * 256 + i) * 5 + tap]);
  }
}

// ---------------- bucketed edge fill ----------------

__global__ void k_fill(const int* __restrict__ srcIdx, const int* __restrict__ dstIdx,
                       int* __restrict__ cnt, int* __restrict__ slot, int E) {
  int e = blockIdx.x * 256 + threadIdx.x;
  if (e < E) {
    int d = dstIdx[e];
    int p = atomicAdd(&cnt[d], 1);
    if (p < CAP) slot[(size_t)d * CAP + p] = srcIdx[e];
  }
}

// per-node segment max over bf16 rows of Bm [*,256]; writes Mm bf16.
// Empty segments stay -inf (bf16 0xFF80): gemm<1>'s relu then yields 0,
// exactly matching PyG's isneginf->0 fill.
__global__ __launch_bounds__(256) void k_maxg(const unsigned short* __restrict__ Bm,
                                              const int* __restrict__ cnt,
                                              const int* __restrict__ slot,
                                              unsigned short* __restrict__ Mm) {
  int node = blockIdx.x * 4 + (threadIdx.x >> 6);
  int lane = threadIdx.x & 63;
  int n = cnt[node];
  if (n > CAP) n = CAP;
  const int* sl = slot + (size_t)node * CAP;
  float4 m = make_float4(-INFINITY, -INFINITY, -INFINITY, -INFINITY);
  int i = 0;
  for (; i + 4 <= n; i += 4) {
    int s0 = sl[i], s1 = sl[i + 1], s2 = sl[i + 2], s3 = sl[i + 3];
    ushort4 v0 = *(const ushort4*)(Bm + (size_t)s0 * 256 + lane * 4);
    ushort4 v1 = *(const ushort4*)(Bm + (size_t)s1 * 256 + lane * 4);
    ushort4 v2 = *(const ushort4*)(Bm + (size_t)s2 * 256 + lane * 4);
    ushort4 v3 = *(const ushort4*)(Bm + (size_t)s3 * 256 + lane * 4);
    m.x = fmaxf(fmaxf(fmaxf(m.x, bf2f(v0.x)), fmaxf(bf2f(v1.x), bf2f(v2.x))), bf2f(v3.x));
    m.y = fmaxf(fmaxf(fmaxf(m.y, bf2f(v0.y)), fmaxf(bf2f(v1.y), bf2f(v2.y))), bf2f(v3.y));
    m.z = fmaxf(fmaxf(fmaxf(m.z, bf2f(v0.z)), fmaxf(bf2f(v1.z), bf2f(v2.z))), bf2f(v3.z));
    m.w = fmaxf(fmaxf(fmaxf(m.w, bf2f(v0.w)), fmaxf(bf2f(v1.w), bf2f(v2.w))), bf2f(v3.w));
  }
  for (; i < n; ++i) {
    int s = sl[i];
    ushort4 v = *(const ushort4*)(Bm + (size_t)s * 256 + lane * 4);
    m.x = fmaxf(m.x, bf2f(v.x));
    m.y = fmaxf(m.y, bf2f(v.y));
    m.z = fmaxf(m.z, bf2f(v.z));
    m.w = fmaxf(m.w, bf2f(v.w));
  }
  ushort4 o;
  o.x = f2bf(m.x); o.y = f2bf(m.y); o.z = f2bf(m.z); o.w = f2bf(m.w);
  *(ushort4*)(Mm + (size_t)node * 256 + lane * 4) = o;
}

// ---------------- MFMA GEMM (64-row x 128-col tiles for grid oversubscription) ----------------
// C[M][256] = A[M][K](bf16) @ Wb^T, Wb [256][K] bf16 (n-major, k-contig)
// MODE 0: C = acc. MODE 1: C = relu(acc + bias + Mm).
template <int MODE>
__global__ __launch_bounds__(256) void k_gemm(const unsigned short* __restrict__ A,
                                              const unsigned short* __restrict__ Wb,
                                              unsigned short* __restrict__ C, int K,
                                              const float* __restrict__ bias,
                                              const unsigned short* __restrict__ Mm) {
  __shared__ __align__(16) short A_lds[64 * 72];
  __shared__ __align__(16) short B_lds[128 * 72];
  int tid = threadIdx.x;
  int row0 = blockIdx.x * 64;
  int col0 = blockIdx.y * 128;
  int lane = tid & 63, wv = tid >> 6;
  int m16 = lane & 15, quad = lane >> 4;
  int sr = tid >> 3, sseg = tid & 7;          // staging: 32 rows x 8 segs per pass

  floatx4 acc[8];
#pragma unroll
  for (int nt = 0; nt < 8; ++nt) acc[nt] = (floatx4){0.f, 0.f, 0.f, 0.f};

  for (int kb = 0; kb < K; kb += 64) {
    __syncthreads();
#pragma unroll
    for (int i = 0; i < 2; ++i) {
      int r = sr + i * 32;
      *(int4*)&A_lds[r * 72 + sseg * 8] =
          *(const int4*)(A + (size_t)(row0 + r) * K + kb + sseg * 8);
    }
#pragma unroll
    for (int i = 0; i < 4; ++i) {
      int r = sr + i * 32;
      *(int4*)&B_lds[r * 72 + sseg * 8] =
          *(const int4*)(Wb + (size_t)(col0 + r) * K + kb + sseg * 8);
    }
    __syncthreads();
#pragma unroll
    for (int ks = 0; ks < 2; ++ks) {
      bhalf8 a = *(const bhalf8*)&A_lds[(wv * 16 + m16) * 72 + ks * 32 + quad * 8];
#pragma unroll
      for (int nt = 0; nt < 8; ++nt) {
        bhalf8 b = *(const bhalf8*)&B_lds[(nt * 16 + m16) * 72 + ks * 32 + quad * 8];
        acc[nt] = __builtin_amdgcn_mfma_f32_16x16x32_bf16(a, b, acc[nt], 0, 0, 0);
      }
    }
  }

  int g0 = row0 + wv * 16 + quad * 4;
#pragma unroll
  for (int nt = 0; nt < 8; ++nt) {
    int c = col0 + nt * 16 + m16;
    float bv = (MODE == 1) ? bias[c] : 0.f;
#pragma unroll
    for (int r = 0; r < 4; ++r) {
      float v = acc[nt][r];
      if (MODE == 1) v = fmaxf(v + bv + bf2f(Mm[(size_t)(g0 + r) * 256 + c]), 0.f);
      C[(size_t)(g0 + r) * 256 + c] = f2bf(v);
    }
  }
}

// ---------------- MFMA temporal conv (64-row x 64-col tiles) ----------------
// Y = maxpool2(relu(conv1d(X, Wtb, k=5, pad=2) + bc)); X bf16 [M][256] as [BN][TRows][256]
// grid (M/64, 4): 64 output rows (one bn sub-tile, halo from global) x 64 cols.
template <int TRows, bool OUT_F32>
__global__ __launch_bounds__(256) void k_conv(const unsigned short* __restrict__ X,
                                              const unsigned short* __restrict__ Wtb,
                                              const float* __restrict__ bc,
                                              void* __restrict__ Yout) {
  const int rowTiles = TRows / 64;
  __shared__ __align__(16) short A_lds[68 * 72];
  __shared__ __align__(16) short B_lds[64 * 72];
  int tid = threadIdx.x;
  int bn = blockIdx.x / rowTiles;
  int t0 = (blockIdx.x % rowTiles) * 64;
  int col0 = blockIdx.y * 64;
  int lane = tid & 63, wv = tid >> 6;
  int m16 = lane & 15, quad = lane >> 4;
  int sr = tid >> 3, sseg = tid & 7;
  const unsigned short* Xbn = X + (size_t)bn * TRows * 256;

  floatx4 acc[4];
#pragma unroll
  for (int nt = 0; nt < 4; ++nt) acc[nt] = (floatx4){0.f, 0.f, 0.f, 0.f};

  for (int kb = 0; kb < 256; kb += 64) {
    __syncthreads();
    // stage A window: bn-local rows [t0-2, t0+66), zero outside [0,TRows)
    for (int u = tid; u < 68 * 8; u += 256) {
      int r = u >> 3, seg = u & 7;
      int t = t0 + r - 2;
      int4 v = {0, 0, 0, 0};
      if (t >= 0 && t < TRows)
        v = *(const int4*)(Xbn + (size_t)t * 256 + kb + seg * 8);
      *(int4*)&A_lds[r * 72 + seg * 8] = v;
    }
    for (int tap = 0; tap < 5; ++tap) {
      if (tap > 0) __syncthreads();
      const unsigned short* Wk = Wtb + (size_t)tap * 65536;
#pragma unroll
      for (int i = 0; i < 2; ++i) {
        int r = sr + i * 32;
        *(int4*)&B_lds[r * 72 + sseg * 8] =
            *(const int4*)(Wk + (size_t)(col0 + r) * 256 + kb + sseg * 8);
      }
      __syncthreads();
#pragma unroll
      for (int ks = 0; ks < 2; ++ks) {
        bhalf8 a = *(const bhalf8*)&A_lds[(wv * 16 + m16 + tap) * 72 + ks * 32 + quad * 8];
#pragma unroll
        for (int nt = 0; nt < 4; ++nt) {
          bhalf8 b = *(const bhalf8*)&B_lds[(nt * 16 + m16) * 72 + ks * 32 + quad * 8];
          acc[nt] = __builtin_amdgcn_mfma_f32_16x16x32_bf16(a, b, acc[nt], 0, 0, 0);
        }
      }
    }
  }

  int gbase = bn * TRows + t0 + wv * 16 + quad * 4;
#pragma unroll
  for (int nt = 0; nt < 4; ++nt) {
    int c = col0 + nt * 16 + m16;
    float bv = bc[c];
    float y0 = fmaxf(acc[nt][0] + bv, 0.f);
    float y1 = fmaxf(acc[nt][1] + bv, 0.f);
    float y2 = fmaxf(acc[nt][2] + bv, 0.f);
    float y3 = fmaxf(acc[nt][3] + bv, 0.f);
    float p0 = fmaxf(y0, y1);
    float p1 = fmaxf(y2, y3);
    int o0 = gbase >> 1;
    if (OUT_F32) {
      float* Y = (float*)Yout;
      Y[(size_t)o0 * 256 + c] = p0;
      Y[(size_t)(o0 + 1) * 256 + c] = p1;
    } else {
      unsigned short* Y = (unsigned short*)Yout;
      Y[(size_t)o0 * 256 + c] = f2bf(p0);
      Y[(size_t)(o0 + 1) * 256 + c] = f2bf(p1);
    }
  }
}

extern "C" void kernel_launch(void* const* d_in, const int* in_sizes, int n_in,
                              void* d_out, int out_size, void* d_ws, size_t ws_size,
                              hipStream_t stream) {
  const float* data = (const float*)d_in[0];
  const int* ei0 = (const int*)d_in[2];
  const int* ei1 = (const int*)d_in[3];
  const float* W0  = (const float*)d_in[4];
  const float* b0  = (const float*)d_in[5];
  const float* Wc0 = (const float*)d_in[6];
  const float* bc0 = (const float*)d_in[7];
  const float* W1  = (const float*)d_in[8];
  const float* b1  = (const float*)d_in[9];
  const float* Wc1 = (const float*)d_in[10];
  const float* bc1 = (const float*)d_in[11];
  float* out = (float*)d_out;

  char* base = (char*)d_ws;
  size_t off = 0;
  auto alloc = [&](size_t bytes) { void* p = base + off; off += (bytes + 255) & ~(size_t)255; return p; };
  unsigned short* X0b   = (unsigned short*)alloc((size_t)NODE0 * Ff * 2);
  unsigned short* Bm    = (unsigned short*)alloc((size_t)NODE0 * Hh * 2);
  unsigned short* Mm    = (unsigned short*)alloc((size_t)NODE0 * Hh * 2);
  unsigned short* X1b   = (unsigned short*)alloc((size_t)NODE0 * Hh * 2);
  unsigned short* Y0b   = (unsigned short*)alloc((size_t)NODE1 * Hh * 2);
  unsigned short* Wbot0 = (unsigned short*)alloc(256 * 128 * 2);
  unsigned short* Wd0   = (unsigned short*)alloc(256 * 128 * 2);
  unsigned short* Wbot1 = (unsigned short*)alloc(256 * 256 * 2);
  unsigned short* Wd1   = (unsigned short*)alloc(256 * 256 * 2);
  unsigned short* Wtb0  = (unsigned short*)alloc(5 * 65536 * 2);
  unsigned short* Wtb1  = (unsigned short*)alloc(5 * 65536 * 2);
  int* cnt0  = (int*)alloc(NODE0 * 4);      // cnt0+cnt1 adjacent: one memset
  int* cnt1  = (int*)alloc(NODE1 * 4);
  int* slot0 = (int*)alloc((size_t)NODE0 * CAP * 4);
  int* slot1 = (int*)alloc((size_t)NODE1 * CAP * 4);

  hipMemsetAsync(cnt0, 0, (NODE0 + NODE1) * sizeof(int), stream);

  k_prep<<<4992, 256, 0, stream>>>(data, X0b, W0, Wbot0, Wd0, W1, Wbot1, Wd1,
                                   Wc0, Wtb0, Wc1, Wtb1);

  // ---- layer 0 ----
  k_fill<<<E0 / 256, 256, 0, stream>>>(ei0, ei0 + E0, cnt0, slot0, E0);
  k_gemm<0><<<dim3(NODE0 / 64, 2), 256, 0, stream>>>(X0b, Wbot0, Bm, 128, nullptr, nullptr);
  k_maxg<<<NODE0 / 4, 256, 0, stream>>>(Bm, cnt0, slot0, Mm);
  k_gemm<1><<<dim3(NODE0 / 64, 2), 256, 0, stream>>>(X0b, Wd0, X1b, 128, b0, Mm);
  k_conv<128, false><<<dim3(NODE0 / 64, 4), 256, 0, stream>>>(X1b, Wtb0, bc0, Y0b);

  // ---- layer 1 ----
  k_fill<<<E1 / 256, 256, 0, stream>>>(ei1, ei1 + E1, cnt1, slot1, E1);
  k_gemm<0><<<dim3(NODE1 / 64, 2), 256, 0, stream>>>(Y0b, Wbot1, Bm, 256, nullptr, nullptr);
  k_maxg<<<NODE1 / 4, 256, 0, stream>>>(Bm, cnt1, slot1, Mm);
  k_gemm<1><<<dim3(NODE1 / 64, 2), 256, 0, stream>>>(Y0b, Wd1, X1b, 256, b1, Mm);
  k_conv<64, true><<<dim3(NODE1 / 64, 4), 256, 0, stream>>>(X1b, Wtb1, bc1, out);
}

// Round 7
// 249.024 us; speedup vs baseline: 1.3608x; 1.0381x over previous
//
#include <hip/hip_runtime.h>
#include <hip/hip_bf16.h>
#include <math.h>

#define T0 128
#define BN 256           // B*N = 8*32
#define Ff 128
#define Hh 256
#define NODE0 32768      // BN*T0
#define E0 262144        // NODE0*8
#define T1 64
#define NODE1 16384      // BN*T1
#define E1 131072
#define CAP 48           // per-node in-edge capacity; deg ~ Poisson(8), P(>48) ~ 1e-25

typedef __attribute__((ext_vector_type(8))) short bhalf8;
typedef __attribute__((ext_vector_type(4))) float floatx4;

__device__ __forceinline__ unsigned short f2bf(float x) {
  union { float f; unsigned u; } v; v.f = x;
  unsigned r = v.u + 0x7fff + ((v.u >> 16) & 1);
  return (unsigned short)(r >> 16);
}
__device__ __forceinline__ float bf2f(unsigned short b) {
  union { unsigned u; float f; } v; v.u = ((unsigned)b) << 16;
  return v.f;
}

// ---------------- fused prep kernel ----------------
// blocks [0,2048): data fp32 [T][BN][F] -> X0b bf16 [bn*T+t][F]
// blocks [2048,2176): W0 -> Wbot0/Wd0 ; [2176,2432): W1 -> Wbot1/Wd1
// blocks [2432,3712): Wc0 -> Wtb0 ; [3712,4992): Wc1 -> Wtb1
__global__ void k_prep(const float* __restrict__ data, unsigned short* __restrict__ X0b,
                       const float* __restrict__ W0, unsigned short* __restrict__ Wbot0,
                       unsigned short* __restrict__ Wd0,
                       const float* __restrict__ W1, unsigned short* __restrict__ Wbot1,
                       unsigned short* __restrict__ Wd1,
                       const float* __restrict__ Wc0, unsigned short* __restrict__ Wtb0,
                       const float* __restrict__ Wc1, unsigned short* __restrict__ Wtb1) {
  int b = blockIdx.x;
  int tid = threadIdx.x;
  if (b < 2048) {
    int idx = b * 256 + tid;          // NODE0*16, 8 elems each
    int c8 = idx & 15;
    int r  = idx >> 4;
    int t  = r & (T0 - 1);
    int bn = r >> 7;
    const float* s = data + ((size_t)t * BN + bn) * Ff + c8 * 8;
    float4 a = *(const float4*)s;
    float4 bb = *(const float4*)(s + 4);
    unsigned short o[8];
    o[0] = f2bf(a.x); o[1] = f2bf(a.y); o[2] = f2bf(a.z); o[3] = f2bf(a.w);
    o[4] = f2bf(bb.x); o[5] = f2bf(bb.y); o[6] = f2bf(bb.z); o[7] = f2bf(bb.w);
    *(int4*)(X0b + ((size_t)(bn * T0 + t) * Ff + c8 * 8)) = *(int4*)o;
  } else if (b < 2176) {
    int idx = (b - 2048) * 256 + tid; // 32768 = 256*128
    int n = idx >> 7, k = idx & 127;
    float top = W0[(size_t)k * 256 + n];
    float bot = W0[(size_t)(128 + k) * 256 + n];
    Wbot0[idx] = f2bf(bot);
    Wd0[idx]   = f2bf(top - bot);
  } else if (b < 2432) {
    int idx = (b - 2176) * 256 + tid; // 65536 = 256*256
    int n = idx >> 8, k = idx & 255;
    float top = W1[(size_t)k * 256 + n];
    float bot = W1[(size_t)(256 + k) * 256 + n];
    Wbot1[idx] = f2bf(bot);
    Wd1[idx]   = f2bf(top - bot);
  } else if (b < 3712) {
    int idx = (b - 2432) * 256 + tid; // 5*65536
    int tap = idx >> 16, o = (idx >> 8) & 255, i = idx & 255;
    Wtb0[idx] = f2bf(Wc0[((size_t)o * 256 + i) * 5 + tap]);
  } else {
    int idx = (b - 3712) * 256 + tid;
    int tap = idx >> 16, o = (idx >> 8) & 255, i = idx & 255;
    Wtb1[idx] = f2bf(Wc1[((size_t)o * 256 + i) * 5 + tap]);
  }
}

// ---------------- bucketed edge fill, both layers in one launch ----------------
__global__ void k_fill(const int* __restrict__ ei0, const int* __restrict__ ei1,
                       int* __restrict__ cnt0, int* __restrict__ cnt1,
                       int* __restrict__ slot0, int* __restrict__ slot1) {
  int e = blockIdx.x * 256 + threadIdx.x;
  if (e < E0) {
    int d = ei0[E0 + e];
    int p = atomicAdd(&cnt0[d], 1);
    if (p < CAP) slot0[(size_t)d * CAP + p] = ei0[e];
  } else {
    int e2 = e - E0;
    int d = ei1[E1 + e2];
    int p = atomicAdd(&cnt1[d], 1);
    if (p < CAP) slot1[(size_t)d * CAP + p] = ei1[e2];
  }
}

// per-node segment max over bf16 rows of Bm [*,256]; writes Mm bf16.
// Empty segments stay -inf (bf16 0xFF80): gemm<1>'s relu then yields 0,
// exactly matching PyG's isneginf->0 fill.
__global__ __launch_bounds__(256) void k_maxg(const unsigned short* __restrict__ Bm,
                                              const int* __restrict__ cnt,
                                              const int* __restrict__ slot,
                                              unsigned short* __restrict__ Mm) {
  int node = blockIdx.x * 4 + (threadIdx.x >> 6);
  int lane = threadIdx.x & 63;
  int n = cnt[node];
  if (n > CAP) n = CAP;
  const int* sl = slot + (size_t)node * CAP;
  float4 m = make_float4(-INFINITY, -INFINITY, -INFINITY, -INFINITY);
  int i = 0;
  for (; i + 4 <= n; i += 4) {
    int s0 = sl[i], s1 = sl[i + 1], s2 = sl[i + 2], s3 = sl[i + 3];
    ushort4 v0 = *(const ushort4*)(Bm + (size_t)s0 * 256 + lane * 4);
    ushort4 v1 = *(const ushort4*)(Bm + (size_t)s1 * 256 + lane * 4);
    ushort4 v2 = *(const ushort4*)(Bm + (size_t)s2 * 256 + lane * 4);
    ushort4 v3 = *(const ushort4*)(Bm + (size_t)s3 * 256 + lane * 4);
    m.x = fmaxf(fmaxf(fmaxf(m.x, bf2f(v0.x)), fmaxf(bf2f(v1.x), bf2f(v2.x))), bf2f(v3.x));
    m.y = fmaxf(fmaxf(fmaxf(m.y, bf2f(v0.y)), fmaxf(bf2f(v1.y), bf2f(v2.y))), bf2f(v3.y));
    m.z = fmaxf(fmaxf(fmaxf(m.z, bf2f(v0.z)), fmaxf(bf2f(v1.z), bf2f(v2.z))), bf2f(v3.z));
    m.w = fmaxf(fmaxf(fmaxf(m.w, bf2f(v0.w)), fmaxf(bf2f(v1.w), bf2f(v2.w))), bf2f(v3.w));
  }
  for (; i < n; ++i) {
    int s = sl[i];
    ushort4 v = *(const ushort4*)(Bm + (size_t)s * 256 + lane * 4);
    m.x = fmaxf(m.x, bf2f(v.x));
    m.y = fmaxf(m.y, bf2f(v.y));
    m.z = fmaxf(m.z, bf2f(v.z));
    m.w = fmaxf(m.w, bf2f(v.w));
  }
  ushort4 o;
  o.x = f2bf(m.x); o.y = f2bf(m.y); o.z = f2bf(m.z); o.w = f2bf(m.w);
  *(ushort4*)(Mm + (size_t)node * 256 + lane * 4) = o;
}

// ---------------- MFMA GEMM (64-row x 128-col tiles) ----------------
// C[M][256] = A[M][K](bf16) @ Wb^T, Wb [256][K] bf16 (n-major, k-contig)
// MODE 0: C = acc. MODE 1: C = relu(acc + bias + Mm).
template <int MODE>
__global__ __launch_bounds__(256) void k_gemm(const unsigned short* __restrict__ A,
                                              const unsigned short* __restrict__ Wb,
                                              unsigned short* __restrict__ C, int K,
                                              const float* __restrict__ bias,
                                              const unsigned short* __restrict__ Mm) {
  __shared__ __align__(16) short A_lds[64 * 72];
  __shared__ __align__(16) short B_lds[128 * 72];
  int tid = threadIdx.x;
  int row0 = blockIdx.x * 64;
  int col0 = blockIdx.y * 128;
  int lane = tid & 63, wv = tid >> 6;
  int m16 = lane & 15, quad = lane >> 4;
  int sr = tid >> 3, sseg = tid & 7;          // staging: 32 rows x 8 segs per pass

  floatx4 acc[8];
#pragma unroll
  for (int nt = 0; nt < 8; ++nt) acc[nt] = (floatx4){0.f, 0.f, 0.f, 0.f};

  for (int kb = 0; kb < K; kb += 64) {
    __syncthreads();
#pragma unroll
    for (int i = 0; i < 2; ++i) {
      int r = sr + i * 32;
      *(int4*)&A_lds[r * 72 + sseg * 8] =
          *(const int4*)(A + (size_t)(row0 + r) * K + kb + sseg * 8);
    }
#pragma unroll
    for (int i = 0; i < 4; ++i) {
      int r = sr + i * 32;
      *(int4*)&B_lds[r * 72 + sseg * 8] =
          *(const int4*)(Wb + (size_t)(col0 + r) * K + kb + sseg * 8);
    }
    __syncthreads();
#pragma unroll
    for (int ks = 0; ks < 2; ++ks) {
      bhalf8 a = *(const bhalf8*)&A_lds[(wv * 16 + m16) * 72 + ks * 32 + quad * 8];
#pragma unroll
      for (int nt = 0; nt < 8; ++nt) {
        bhalf8 b = *(const bhalf8*)&B_lds[(nt * 16 + m16) * 72 + ks * 32 + quad * 8];
        acc[nt] = __builtin_amdgcn_mfma_f32_16x16x32_bf16(a, b, acc[nt], 0, 0, 0);
      }
    }
  }

  int g0 = row0 + wv * 16 + quad * 4;
#pragma unroll
  for (int nt = 0; nt < 8; ++nt) {
    int c = col0 + nt * 16 + m16;
    float bv = (MODE == 1) ? bias[c] : 0.f;
#pragma unroll
    for (int r = 0; r < 4; ++r) {
      float v = acc[nt][r];
      if (MODE == 1) v = fmaxf(v + bv + bf2f(Mm[(size_t)(g0 + r) * 256 + c]), 0.f);
      C[(size_t)(g0 + r) * 256 + c] = f2bf(v);
    }
  }
}

// ---------------- MFMA temporal conv (all-taps-staged, 128-row x 64-col) ----------------
// Y = maxpool2(relu(conv1d(X, Wtb, k=5, pad=2) + bc)); X bf16 [M][256] as [BN][TRows][256]
// Block: 128 output rows (2 subtiles of 64, each with its own 68-row halo window so
// bn boundaries stay correct for TRows=64) x 64 cols. Per K-chunk of 32: stage A
// windows + B for ALL 5 taps, then 40 MFMAs/wave out of LDS. 16 barriers total.
template <int TRows, bool OUT_F32>
__global__ __launch_bounds__(256) void k_conv(const unsigned short* __restrict__ X,
                                              const unsigned short* __restrict__ Wtb,
                                              const float* __restrict__ bc,
                                              void* __restrict__ Yout) {
  __shared__ __align__(16) short A_lds[2 * 68 * 40];   // [s][row 0..67][k 32 + pad 8]
  __shared__ __align__(16) short B_lds[320 * 40];      // [tap*64 + col][k 32 + pad 8]
  int tid = threadIdx.x;
  int row0 = blockIdx.x * 128;
  int col0 = blockIdx.y * 64;
  int lane = tid & 63, wv = tid >> 6;
  int m16 = lane & 15, quad = lane >> 4;

  floatx4 acc[2][4];
#pragma unroll
  for (int s = 0; s < 2; ++s)
#pragma unroll
    for (int nt = 0; nt < 4; ++nt) acc[s][nt] = (floatx4){0.f, 0.f, 0.f, 0.f};

  for (int kb = 0; kb < 256; kb += 32) {
    __syncthreads();
    // stage A: two 68-row halo windows (rows base-2 .. base+66), zero outside bn
    for (int u = tid; u < 544; u += 256) {
      int s = (u >= 272) ? 1 : 0;
      int v = u - s * 272;
      int rr = v >> 2, seg = v & 3;
      int base = row0 + s * 64;
      int lo = base & ~(TRows - 1);
      int g = base + rr - 2;
      int4 val = {0, 0, 0, 0};
      if (g >= lo && g < lo + TRows)
        val = *(const int4*)(X + (size_t)g * 256 + kb + seg * 8);
      *(int4*)&A_lds[(s * 68 + rr) * 40 + seg * 8] = val;
    }
    // stage B: all 5 taps x 64 cols x 32 k
#pragma unroll
    for (int i = 0; i < 5; ++i) {
      int u = tid + i * 256;          // 320 rows x 4 segs
      int r = u >> 2, seg = u & 3;    // r = tap*64 + col
      int tap = r >> 6, col = r & 63;
      *(int4*)&B_lds[r * 40 + seg * 8] =
          *(const int4*)(Wtb + (size_t)tap * 65536 + (size_t)(col0 + col) * 256 + kb + seg * 8);
    }
    __syncthreads();
#pragma unroll
    for (int tap = 0; tap < 5; ++tap) {
      bhalf8 a0 = *(const bhalf8*)&A_lds[(wv * 16 + m16 + tap) * 40 + quad * 8];
      bhalf8 a1 = *(const bhalf8*)&A_lds[(68 + wv * 16 + m16 + tap) * 40 + quad * 8];
#pragma unroll
      for (int nt = 0; nt < 4; ++nt) {
        bhalf8 b = *(const bhalf8*)&B_lds[((tap << 6) + nt * 16 + m16) * 40 + quad * 8];
        acc[0][nt] = __builtin_amdgcn_mfma_f32_16x16x32_bf16(a0, b, acc[0][nt], 0, 0, 0);
        acc[1][nt] = __builtin_amdgcn_mfma_f32_16x16x32_bf16(a1, b, acc[1][nt], 0, 0, 0);
      }
    }
  }

#pragma unroll
  for (int s = 0; s < 2; ++s) {
    int gbase = row0 + s * 64 + wv * 16 + quad * 4;
#pragma unroll
    for (int nt = 0; nt < 4; ++nt) {
      int c = col0 + nt * 16 + m16;
      float bv = bc[c];
      float y0 = fmaxf(acc[s][nt][0] + bv, 0.f);
      float y1 = fmaxf(acc[s][nt][1] + bv, 0.f);
      float y2 = fmaxf(acc[s][nt][2] + bv, 0.f);
      float y3 = fmaxf(acc[s][nt][3] + bv, 0.f);
      float p0 = fmaxf(y0, y1);
      float p1 = fmaxf(y2, y3);
      int o0 = gbase >> 1;
      if (OUT_F32) {
        float* Y = (float*)Yout;
        Y[(size_t)o0 * 256 + c] = p0;
        Y[(size_t)(o0 + 1) * 256 + c] = p1;
      } else {
        unsigned short* Y = (unsigned short*)Yout;
        Y[(size_t)o0 * 256 + c] = f2bf(p0);
        Y[(size_t)(o0 + 1) * 256 + c] = f2bf(p1);
      }
    }
  }
}

extern "C" void kernel_launch(void* const* d_in, const int* in_sizes, int n_in,
                              void* d_out, int out_size, void* d_ws, size_t ws_size,
                              hipStream_t stream) {
  const float* data = (const float*)d_in[0];
  const int* ei0 = (const int*)d_in[2];
  const int* ei1 = (const int*)d_in[3];
  const float* W0  = (const float*)d_in[4];
  const float* b0  = (const float*)d_in[5];
  const float* Wc0 = (const float*)d_in[6];
  const float* bc0 = (const float*)d_in[7];
  const float* W1  = (const float*)d_in[8];
  const float* b1  = (const float*)d_in[9];
  const float* Wc1 = (const float*)d_in[10];
  const float* bc1 = (const float*)d_in[11];
  float* out = (float*)d_out;

  char* base = (char*)d_ws;
  size_t off = 0;
  auto alloc = [&](size_t bytes) { void* p = base + off; off += (bytes + 255) & ~(size_t)255; return p; };
  unsigned short* X0b   = (unsigned short*)alloc((size_t)NODE0 * Ff * 2);
  unsigned short* Bm    = (unsigned short*)alloc((size_t)NODE0 * Hh * 2);
  unsigned short* Mm    = (unsigned short*)alloc((size_t)NODE0 * Hh * 2);
  unsigned short* X1b   = (unsigned short*)alloc((size_t)NODE0 * Hh * 2);
  unsigned short* Y0b   = (unsigned short*)alloc((size_t)NODE1 * Hh * 2);
  unsigned short* Wbot0 = (unsigned short*)alloc(256 * 128 * 2);
  unsigned short* Wd0   = (unsigned short*)alloc(256 * 128 * 2);
  unsigned short* Wbot1 = (unsigned short*)alloc(256 * 256 * 2);
  unsigned short* Wd1   = (unsigned short*)alloc(256 * 256 * 2);
  unsigned short* Wtb0  = (unsigned short*)alloc(5 * 65536 * 2);
  unsigned short* Wtb1  = (unsigned short*)alloc(5 * 65536 * 2);
  int* cnt0  = (int*)alloc(NODE0 * 4);      // cnt0+cnt1 adjacent: one memset
  int* cnt1  = (int*)alloc(NODE1 * 4);
  int* slot0 = (int*)alloc((size_t)NODE0 * CAP * 4);
  int* slot1 = (int*)alloc((size_t)NODE1 * CAP * 4);

  hipMemsetAsync(cnt0, 0, (NODE0 + NODE1) * sizeof(int), stream);

  k_prep<<<4992, 256, 0, stream>>>(data, X0b, W0, Wbot0, Wd0, W1, Wbot1, Wd1,
                                   Wc0, Wtb0, Wc1, Wtb1);
  k_fill<<<(E0 + E1) / 256, 256, 0, stream>>>(ei0, ei1, cnt0, cnt1, slot0, slot1);

  // ---- layer 0 ----
  k_gemm<0><<<dim3(NODE0 / 64, 2), 256, 0, stream>>>(X0b, Wbot0, Bm, 128, nullptr, nullptr);
  k_maxg<<<NODE0 / 4, 256, 0, stream>>>(Bm, cnt0, slot0, Mm);
  k_gemm<1><<<dim3(NODE0 / 64, 2), 256, 0, stream>>>(X0b, Wd0, X1b, 128, b0, Mm);
  k_conv<128, false><<<dim3(NODE0 / 128, 4), 256, 0, stream>>>(X1b, Wtb0, bc0, Y0b);

  // ---- layer 1 ----
  k_gemm<0><<<dim3(NODE1 / 64, 2), 256, 0, stream>>>(Y0b, Wbot1, Bm, 256, nullptr, nullptr);
  k_maxg<<<NODE1 / 4, 256, 0, stream>>>(Bm, cnt1, slot1, Mm);
  k_gemm<1><<<dim3(NODE1 / 64, 2), 256, 0, stream>>>(Y0b, Wd1, X1b, 256, b1, Mm);
  k_conv<64, true><<<dim3(NODE1 / 128, 4), 256, 0, stream>>>(X1b, Wtb1, bc1, out);
}

// Round 8
// 226.750 us; speedup vs baseline: 1.4945x; 1.0982x over previous
//
#include <hip/hip_runtime.h>
#include <hip/hip_bf16.h>
#include <math.h>

#define T0 128
#define BN 256           // B*N = 8*32
#define Ff 128
#define Hh 256
#define NODE0 32768      // BN*T0
#define E0 262144        // NODE0*8
#define T1 64
#define NODE1 16384      // BN*T1
#define E1 131072
#define CAP 48           // per-node in-edge capacity; deg ~ Poisson(8), P(>48) ~ 1e-25

typedef __attribute__((ext_vector_type(8))) short bhalf8;
typedef __attribute__((ext_vector_type(4))) float floatx4;
typedef __attribute__((ext_vector_type(16))) float floatx16;

__device__ __forceinline__ unsigned short f2bf(float x) {
  union { float f; unsigned u; } v; v.f = x;
  unsigned r = v.u + 0x7fff + ((v.u >> 16) & 1);
  return (unsigned short)(r >> 16);
}
__device__ __forceinline__ float bf2f(unsigned short b) {
  union { unsigned u; float f; } v; v.u = ((unsigned)b) << 16;
  return v.f;
}

// ---------------- fused prep + edge-fill kernel ----------------
// blocks [0,2048): data fp32 [T][BN][F] -> X0b bf16 [bn*T+t][F]
// [2048,2176): W0 -> Wbot0/Wd0 ; [2176,2432): W1 -> Wbot1/Wd1
// [2432,3712): Wc0 -> Wtb0 ; [3712,4992): Wc1 -> Wtb1
// [4992,6528): bucketed edge fill for both layers
__global__ void k_prepfill(const float* __restrict__ data, unsigned short* __restrict__ X0b,
                           const float* __restrict__ W0, unsigned short* __restrict__ Wbot0,
                           unsigned short* __restrict__ Wd0,
                           const float* __restrict__ W1, unsigned short* __restrict__ Wbot1,
                           unsigned short* __restrict__ Wd1,
                           const float* __restrict__ Wc0, unsigned short* __restrict__ Wtb0,
                           const float* __restrict__ Wc1, unsigned short* __restrict__ Wtb1,
                           const int* __restrict__ ei0, const int* __restrict__ ei1,
                           int* __restrict__ cnt0, int* __restrict__ cnt1,
                           int* __restrict__ slot0, int* __restrict__ slot1) {
  int b = blockIdx.x;
  int tid = threadIdx.x;
  if (b < 2048) {
    int idx = b * 256 + tid;          // NODE0*16, 8 elems each
    int c8 = idx & 15;
    int r  = idx >> 4;
    int t  = r & (T0 - 1);
    int bn = r >> 7;
    const float* s = data + ((size_t)t * BN + bn) * Ff + c8 * 8;
    float4 a = *(const float4*)s;
    float4 bb = *(const float4*)(s + 4);
    unsigned short o[8];
    o[0] = f2bf(a.x); o[1] = f2bf(a.y); o[2] = f2bf(a.z); o[3] = f2bf(a.w);
    o[4] = f2bf(bb.x); o[5] = f2bf(bb.y); o[6] = f2bf(bb.z); o[7] = f2bf(bb.w);
    *(int4*)(X0b + ((size_t)(bn * T0 + t) * Ff + c8 * 8)) = *(int4*)o;
  } else if (b < 2176) {
    int idx = (b - 2048) * 256 + tid; // 32768 = 256*128
    int n = idx >> 7, k = idx & 127;
    float top = W0[(size_t)k * 256 + n];
    float bot = W0[(size_t)(128 + k) * 256 + n];
    Wbot0[idx] = f2bf(bot);
    Wd0[idx]   = f2bf(top - bot);
  } else if (b < 2432) {
    int idx = (b - 2176) * 256 + tid; // 65536 = 256*256
    int n = idx >> 8, k = idx & 255;
    float top = W1[(size_t)k * 256 + n];
    float bot = W1[(size_t)(256 + k) * 256 + n];
    Wbot1[idx] = f2bf(bot);
    Wd1[idx]   = f2bf(top - bot);
  } else if (b < 3712) {
    int idx = (b - 2432) * 256 + tid; // 5*65536
    int tap = idx >> 16, o = (idx >> 8) & 255, i = idx & 255;
    Wtb0[idx] = f2bf(Wc0[((size_t)o * 256 + i) * 5 + tap]);
  } else if (b < 4992) {
    int idx = (b - 3712) * 256 + tid;
    int tap = idx >> 16, o = (idx >> 8) & 255, i = idx & 255;
    Wtb1[idx] = f2bf(Wc1[((size_t)o * 256 + i) * 5 + tap]);
  } else {
    int e = (b - 4992) * 256 + tid;   // E0+E1 = 393216 over 1536 blocks
    if (e < E0) {
      int d = ei0[E0 + e];
      int p = atomicAdd(&cnt0[d], 1);
      if (p < CAP) slot0[(size_t)d * CAP + p] = ei0[e];
    } else {
      int e2 = e - E0;
      int d = ei1[E1 + e2];
      int p = atomicAdd(&cnt1[d], 1);
      if (p < CAP) slot1[(size_t)d * CAP + p] = ei1[e2];
    }
  }
}

// ---------------- dual-output MFMA GEMM ----------------
// grid.y g in [0,4): g<2 -> Bm cols (g&1)*128 = A@Wbot (bf16)
//                    g>=2 -> P cols (g&1)*128 = A@Wd + bias (fp32)
__global__ __launch_bounds__(256) void k_gemm2(const unsigned short* __restrict__ A,
                                               const unsigned short* __restrict__ Wbot,
                                               const unsigned short* __restrict__ Wd,
                                               unsigned short* __restrict__ Bm,
                                               float* __restrict__ P, int K,
                                               const float* __restrict__ bias) {
  __shared__ __align__(16) short A_lds[64 * 72];
  __shared__ __align__(16) short B_lds[128 * 72];
  int tid = threadIdx.x;
  int row0 = blockIdx.x * 64;
  int g = blockIdx.y;
  int col0 = (g & 1) * 128;
  const unsigned short* Wb = (g < 2) ? Wbot : Wd;
  int lane = tid & 63, wv = tid >> 6;
  int m16 = lane & 15, quad = lane >> 4;
  int sr = tid >> 3, sseg = tid & 7;

  floatx4 acc[8];
#pragma unroll
  for (int nt = 0; nt < 8; ++nt) acc[nt] = (floatx4){0.f, 0.f, 0.f, 0.f};

  for (int kb = 0; kb < K; kb += 64) {
    __syncthreads();
#pragma unroll
    for (int i = 0; i < 2; ++i) {
      int r = sr + i * 32;
      *(int4*)&A_lds[r * 72 + sseg * 8] =
          *(const int4*)(A + (size_t)(row0 + r) * K + kb + sseg * 8);
    }
#pragma unroll
    for (int i = 0; i < 4; ++i) {
      int r = sr + i * 32;
      *(int4*)&B_lds[r * 72 + sseg * 8] =
          *(const int4*)(Wb + (size_t)(col0 + r) * K + kb + sseg * 8);
    }
    __syncthreads();
#pragma unroll
    for (int ks = 0; ks < 2; ++ks) {
      bhalf8 a = *(const bhalf8*)&A_lds[(wv * 16 + m16) * 72 + ks * 32 + quad * 8];
#pragma unroll
      for (int nt = 0; nt < 8; ++nt) {
        bhalf8 b = *(const bhalf8*)&B_lds[(nt * 16 + m16) * 72 + ks * 32 + quad * 8];
        acc[nt] = __builtin_amdgcn_mfma_f32_16x16x32_bf16(a, b, acc[nt], 0, 0, 0);
      }
    }
  }

  int g0 = row0 + wv * 16 + quad * 4;
  if (g < 2) {
#pragma unroll
    for (int nt = 0; nt < 8; ++nt) {
      int c = col0 + nt * 16 + m16;
#pragma unroll
      for (int r = 0; r < 4; ++r)
        Bm[(size_t)(g0 + r) * 256 + c] = f2bf(acc[nt][r]);
    }
  } else {
#pragma unroll
    for (int nt = 0; nt < 8; ++nt) {
      int c = col0 + nt * 16 + m16;
      float bv = bias[c];
#pragma unroll
      for (int r = 0; r < 4; ++r)
        P[(size_t)(g0 + r) * 256 + c] = acc[nt][r] + bv;
    }
  }
}

// ---------------- segment max + fused relu epilogue ----------------
// per node: M = max over in-edge sources of Bm rows (-inf if empty),
// X1 = relu(P + M)  (empty -> relu(-inf) = 0, matching PyG fill)
__global__ __launch_bounds__(256) void k_maxg2(const unsigned short* __restrict__ Bm,
                                               const int* __restrict__ cnt,
                                               const int* __restrict__ slot,
                                               const float* __restrict__ P,
                                               unsigned short* __restrict__ X1) {
  int node = blockIdx.x * 4 + (threadIdx.x >> 6);
  int lane = threadIdx.x & 63;
  int n = cnt[node];
  if (n > CAP) n = CAP;
  const int* sl = slot + (size_t)node * CAP;
  float4 m = make_float4(-INFINITY, -INFINITY, -INFINITY, -INFINITY);
  int i = 0;
  for (; i + 4 <= n; i += 4) {
    int s0 = sl[i], s1 = sl[i + 1], s2 = sl[i + 2], s3 = sl[i + 3];
    ushort4 v0 = *(const ushort4*)(Bm + (size_t)s0 * 256 + lane * 4);
    ushort4 v1 = *(const ushort4*)(Bm + (size_t)s1 * 256 + lane * 4);
    ushort4 v2 = *(const ushort4*)(Bm + (size_t)s2 * 256 + lane * 4);
    ushort4 v3 = *(const ushort4*)(Bm + (size_t)s3 * 256 + lane * 4);
    m.x = fmaxf(fmaxf(fmaxf(m.x, bf2f(v0.x)), fmaxf(bf2f(v1.x), bf2f(v2.x))), bf2f(v3.x));
    m.y = fmaxf(fmaxf(fmaxf(m.y, bf2f(v0.y)), fmaxf(bf2f(v1.y), bf2f(v2.y))), bf2f(v3.y));
    m.z = fmaxf(fmaxf(fmaxf(m.z, bf2f(v0.z)), fmaxf(bf2f(v1.z), bf2f(v2.z))), bf2f(v3.z));
    m.w = fmaxf(fmaxf(fmaxf(m.w, bf2f(v0.w)), fmaxf(bf2f(v1.w), bf2f(v2.w))), bf2f(v3.w));
  }
  for (; i < n; ++i) {
    int s = sl[i];
    ushort4 v = *(const ushort4*)(Bm + (size_t)s * 256 + lane * 4);
    m.x = fmaxf(m.x, bf2f(v.x));
    m.y = fmaxf(m.y, bf2f(v.y));
    m.z = fmaxf(m.z, bf2f(v.z));
    m.w = fmaxf(m.w, bf2f(v.w));
  }
  float4 p = *(const float4*)(P + (size_t)node * 256 + lane * 4);
  ushort4 o;
  o.x = f2bf(fmaxf(p.x + m.x, 0.f));
  o.y = f2bf(fmaxf(p.y + m.y, 0.f));
  o.z = f2bf(fmaxf(p.z + m.z, 0.f));
  o.w = f2bf(fmaxf(p.w + m.w, 0.f));
  *(ushort4*)(X1 + (size_t)node * 256 + lane * 4) = o;
}

// ---------------- MFMA temporal conv: 32x32x16, all taps staged ----------------
// Y = maxpool2(relu(conv1d(X, Wtb, k=5, pad=2) + bc)); X bf16 [M][256] as [BN][TRows][256]
// Block: 128 rows x (NT*64) cols, 4 waves. Wave w: row half h=(w&1) (2 row-tiles of 32),
// col part c=(w>>1) (NT col-tiles of 32). Per K-chunk of 32: stage 2 halo windows of A
// + all 5 taps of B, then 5*2*(2+NT) ds_reads -> 5*2*2*NT MFMAs per wave.
// C/D layout (32x32): col=lane&31, row=(reg&3)+8*(reg>>2)+4*(lane>>5); pool pairs are
// adjacent regs in the same lane.
template <int TRows, int NT, bool OUT_F32>
__global__ __launch_bounds__(256) void k_conv32(const unsigned short* __restrict__ X,
                                                const unsigned short* __restrict__ Wtb,
                                                const float* __restrict__ bc,
                                                void* __restrict__ Yout) {
  const int CB = NT * 64;                        // block cols
  __shared__ __align__(16) short A_lds[2 * 68 * 40];   // [win][row 0..67][k32 + pad8]
  __shared__ __align__(16) short B_lds[5 * CB * 40];   // [tap*CB + col][k32 + pad8]
  int tid = threadIdx.x;
  int row0 = blockIdx.x * 128;
  int col0 = blockIdx.y * CB;
  int lane = tid & 63, wv = tid >> 6;
  int l31 = lane & 31, khalf = lane >> 5;
  int h = wv & 1, cpart = wv >> 1;

  floatx16 acc[2][NT];
#pragma unroll
  for (int rt = 0; rt < 2; ++rt)
#pragma unroll
    for (int ct = 0; ct < NT; ++ct)
#pragma unroll
      for (int r = 0; r < 16; ++r) acc[rt][ct][r] = 0.f;

  for (int kb = 0; kb < 256; kb += 32) {
    __syncthreads();
    // stage A: two 68-row halo windows (rows base-2 .. base+66), zero outside bn
    for (int u = tid; u < 544; u += 256) {
      int s = (u >= 272) ? 1 : 0;
      int v = u - s * 272;
      int rr = v >> 2, seg = v & 3;
      int base = row0 + s * 64;
      int lo = base & ~(TRows - 1);
      int gr = base + rr - 2;
      int4 val = {0, 0, 0, 0};
      if (gr >= lo && gr < lo + TRows)
        val = *(const int4*)(X + (size_t)gr * 256 + kb + seg * 8);
      *(int4*)&A_lds[(s * 68 + rr) * 40 + seg * 8] = val;
    }
    // stage B: 5 taps x CB cols x 32 k
#pragma unroll
    for (int i = 0; i < 5 * NT; ++i) {
      int u = tid + i * 256;            // 5*CB rows x 4 segs
      int r = u >> 2, seg = u & 3;      // r = tap*CB + col
      int tap = r / CB, col = r % CB;
      *(int4*)&B_lds[r * 40 + seg * 8] =
          *(const int4*)(Wtb + (size_t)tap * 65536 + (size_t)(col0 + col) * 256 + kb + seg * 8);
    }
    __syncthreads();
#pragma unroll
    for (int tap = 0; tap < 5; ++tap) {
#pragma unroll
      for (int ks = 0; ks < 2; ++ks) {
        int ko = ks * 16 + khalf * 8;
        bhalf8 a[2];
#pragma unroll
        for (int rt = 0; rt < 2; ++rt)
          a[rt] = *(const bhalf8*)&A_lds[(h * 68 + rt * 32 + l31 + tap) * 40 + ko];
#pragma unroll
        for (int ct = 0; ct < NT; ++ct) {
          bhalf8 b = *(const bhalf8*)&B_lds[(tap * CB + cpart * NT * 32 + ct * 32 + l31) * 40 + ko];
#pragma unroll
          for (int rt = 0; rt < 2; ++rt)
            acc[rt][ct] = __builtin_amdgcn_mfma_f32_32x32x16_bf16(a[rt], b, acc[rt][ct], 0, 0, 0);
        }
      }
    }
  }

#pragma unroll
  for (int rt = 0; rt < 2; ++rt) {
#pragma unroll
    for (int ct = 0; ct < NT; ++ct) {
      int c = col0 + cpart * NT * 32 + ct * 32 + l31;
      float bv = bc[c];
#pragma unroll
      for (int r = 0; r < 16; r += 2) {
        int rowg = row0 + h * 64 + rt * 32 + 4 * khalf + 8 * (r >> 2) + (r & 3);
        float y0 = fmaxf(acc[rt][ct][r] + bv, 0.f);
        float y1 = fmaxf(acc[rt][ct][r + 1] + bv, 0.f);
        float p = fmaxf(y0, y1);
        int o = rowg >> 1;
        if (OUT_F32) ((float*)Yout)[(size_t)o * 256 + c] = p;
        else ((unsigned short*)Yout)[(size_t)o * 256 + c] = f2bf(p);
      }
    }
  }
}

extern "C" void kernel_launch(void* const* d_in, const int* in_sizes, int n_in,
                              void* d_out, int out_size, void* d_ws, size_t ws_size,
                              hipStream_t stream) {
  const float* data = (const float*)d_in[0];
  const int* ei0 = (const int*)d_in[2];
  const int* ei1 = (const int*)d_in[3];
  const float* W0  = (const float*)d_in[4];
  const float* b0  = (const float*)d_in[5];
  const float* Wc0 = (const float*)d_in[6];
  const float* bc0 = (const float*)d_in[7];
  const float* W1  = (const float*)d_in[8];
  const float* b1  = (const float*)d_in[9];
  const float* Wc1 = (const float*)d_in[10];
  const float* bc1 = (const float*)d_in[11];
  float* out = (float*)d_out;

  char* base = (char*)d_ws;
  size_t off = 0;
  auto alloc = [&](size_t bytes) { void* p = base + off; off += (bytes + 255) & ~(size_t)255; return p; };
  unsigned short* X0b   = (unsigned short*)alloc((size_t)NODE0 * Ff * 2);
  unsigned short* Bm    = (unsigned short*)alloc((size_t)NODE0 * Hh * 2);
  float*          P     = (float*)alloc((size_t)NODE0 * Hh * 4);
  unsigned short* X1b   = (unsigned short*)alloc((size_t)NODE0 * Hh * 2);
  unsigned short* Y0b   = (unsigned short*)alloc((size_t)NODE1 * Hh * 2);
  unsigned short* Wbot0 = (unsigned short*)alloc(256 * 128 * 2);
  unsigned short* Wd0   = (unsigned short*)alloc(256 * 128 * 2);
  unsigned short* Wbot1 = (unsigned short*)alloc(256 * 256 * 2);
  unsigned short* Wd1   = (unsigned short*)alloc(256 * 256 * 2);
  unsigned short* Wtb0  = (unsigned short*)alloc(5 * 65536 * 2);
  unsigned short* Wtb1  = (unsigned short*)alloc(5 * 65536 * 2);
  int* cnt0  = (int*)alloc(NODE0 * 4);      // cnt0+cnt1 adjacent: one memset
  int* cnt1  = (int*)alloc(NODE1 * 4);
  int* slot0 = (int*)alloc((size_t)NODE0 * CAP * 4);
  int* slot1 = (int*)alloc((size_t)NODE1 * CAP * 4);

  hipMemsetAsync(cnt0, 0, (NODE0 + NODE1) * sizeof(int), stream);

  k_prepfill<<<6528, 256, 0, stream>>>(data, X0b, W0, Wbot0, Wd0, W1, Wbot1, Wd1,
                                       Wc0, Wtb0, Wc1, Wtb1,
                                       ei0, ei1, cnt0, cnt1, slot0, slot1);

  // ---- layer 0 ----
  k_gemm2<<<dim3(NODE0 / 64, 4), 256, 0, stream>>>(X0b, Wbot0, Wd0, Bm, P, 128, b0);
  k_maxg2<<<NODE0 / 4, 256, 0, stream>>>(Bm, cnt0, slot0, P, X1b);
  k_conv32<128, 2, false><<<dim3(NODE0 / 128, 2), 256, 0, stream>>>(X1b, Wtb0, bc0, Y0b);

  // ---- layer 1 ----
  k_gemm2<<<dim3(NODE1 / 64, 4), 256, 0, stream>>>(Y0b, Wbot1, Wd1, Bm, P, 256, b1);
  k_maxg2<<<NODE1 / 4, 256, 0, stream>>>(Bm, cnt1, slot1, P, X1b);
  k_conv32<64, 1, true><<<dim3(NODE1 / 128, 4), 256, 0, stream>>>(X1b, Wtb1, bc1, out);
}

// Round 9
// 223.835 us; speedup vs baseline: 1.5140x; 1.0130x over previous
//
#include <hip/hip_runtime.h>
#include <hip/hip_bf16.h>
#include <math.h>

#define T0 128
#define BN 256           // B*N = 8*32
#define Ff 128
#define Hh 256
#define NODE0 32768      // BN*T0
#define E0 262144        // NODE0*8
#define T1 64
#define NODE1 16384      // BN*T1
#define E1 131072
#define CAP 48           // per-node in-edge capacity; deg ~ Poisson(8), P(>48) ~ 1e-25

typedef __attribute__((ext_vector_type(8))) short bhalf8;
typedef __attribute__((ext_vector_type(4))) float floatx4;
typedef __attribute__((ext_vector_type(16))) float floatx16;

__device__ __forceinline__ unsigned short f2bf(float x) {
  union { float f; unsigned u; } v; v.f = x;
  unsigned r = v.u + 0x7fff + ((v.u >> 16) & 1);
  return (unsigned short)(r >> 16);
}
__device__ __forceinline__ float bf2f(unsigned short b) {
  union { unsigned u; float f; } v; v.u = ((unsigned)b) << 16;
  return v.f;
}

// ---------------- fused prep + edge-fill kernel ----------------
// blocks [0,2048): data fp32 [T][BN][F] -> X0b bf16 [bn*T+t][F]
// [2048,2176): W0 -> Wbot0/Wd0 ; [2176,2432): W1 -> Wbot1/Wd1
// [2432,3712): Wc0 -> Wtb0 ; [3712,4992): Wc1 -> Wtb1
// [4992,6528): bucketed edge fill for both layers
__global__ void k_prepfill(const float* __restrict__ data, unsigned short* __restrict__ X0b,
                           const float* __restrict__ W0, unsigned short* __restrict__ Wbot0,
                           unsigned short* __restrict__ Wd0,
                           const float* __restrict__ W1, unsigned short* __restrict__ Wbot1,
                           unsigned short* __restrict__ Wd1,
                           const float* __restrict__ Wc0, unsigned short* __restrict__ Wtb0,
                           const float* __restrict__ Wc1, unsigned short* __restrict__ Wtb1,
                           const int* __restrict__ ei0, const int* __restrict__ ei1,
                           int* __restrict__ cnt0, int* __restrict__ cnt1,
                           int* __restrict__ slot0, int* __restrict__ slot1) {
  int b = blockIdx.x;
  int tid = threadIdx.x;
  if (b < 2048) {
    int idx = b * 256 + tid;          // NODE0*16, 8 elems each
    int c8 = idx & 15;
    int r  = idx >> 4;
    int t  = r & (T0 - 1);
    int bn = r >> 7;
    const float* s = data + ((size_t)t * BN + bn) * Ff + c8 * 8;
    float4 a = *(const float4*)s;
    float4 bb = *(const float4*)(s + 4);
    unsigned short o[8];
    o[0] = f2bf(a.x); o[1] = f2bf(a.y); o[2] = f2bf(a.z); o[3] = f2bf(a.w);
    o[4] = f2bf(bb.x); o[5] = f2bf(bb.y); o[6] = f2bf(bb.z); o[7] = f2bf(bb.w);
    *(int4*)(X0b + ((size_t)(bn * T0 + t) * Ff + c8 * 8)) = *(int4*)o;
  } else if (b < 2176) {
    int idx = (b - 2048) * 256 + tid; // 32768 = 256*128
    int n = idx >> 7, k = idx & 127;
    float top = W0[(size_t)k * 256 + n];
    float bot = W0[(size_t)(128 + k) * 256 + n];
    Wbot0[idx] = f2bf(bot);
    Wd0[idx]   = f2bf(top - bot);
  } else if (b < 2432) {
    int idx = (b - 2176) * 256 + tid; // 65536 = 256*256
    int n = idx >> 8, k = idx & 255;
    float top = W1[(size_t)k * 256 + n];
    float bot = W1[(size_t)(256 + k) * 256 + n];
    Wbot1[idx] = f2bf(bot);
    Wd1[idx]   = f2bf(top - bot);
  } else if (b < 3712) {
    int idx = (b - 2432) * 256 + tid; // 5*65536
    int tap = idx >> 16, o = (idx >> 8) & 255, i = idx & 255;
    Wtb0[idx] = f2bf(Wc0[((size_t)o * 256 + i) * 5 + tap]);
  } else if (b < 4992) {
    int idx = (b - 3712) * 256 + tid;
    int tap = idx >> 16, o = (idx >> 8) & 255, i = idx & 255;
    Wtb1[idx] = f2bf(Wc1[((size_t)o * 256 + i) * 5 + tap]);
  } else {
    int e = (b - 4992) * 256 + tid;   // E0+E1 = 393216 over 1536 blocks
    if (e < E0) {
      int d = ei0[E0 + e];
      int p = atomicAdd(&cnt0[d], 1);
      if (p < CAP) slot0[(size_t)d * CAP + p] = ei0[e];
    } else {
      int e2 = e - E0;
      int d = ei1[E1 + e2];
      int p = atomicAdd(&cnt1[d], 1);
      if (p < CAP) slot1[(size_t)d * CAP + p] = ei1[e2];
    }
  }
}

// ---------------- dual-output MFMA GEMM ----------------
// grid.y g in [0,4): g<2 -> Bm cols (g&1)*128 = A@Wbot (bf16)
//                    g>=2 -> P cols (g&1)*128 = A@Wd + bias (bf16)
__global__ __launch_bounds__(256) void k_gemm2(const unsigned short* __restrict__ A,
                                               const unsigned short* __restrict__ Wbot,
                                               const unsigned short* __restrict__ Wd,
                                               unsigned short* __restrict__ Bm,
                                               unsigned short* __restrict__ P, int K,
                                               const float* __restrict__ bias) {
  __shared__ __align__(16) short A_lds[64 * 72];
  __shared__ __align__(16) short B_lds[128 * 72];
  int tid = threadIdx.x;
  int row0 = blockIdx.x * 64;
  int g = blockIdx.y;
  int col0 = (g & 1) * 128;
  const unsigned short* Wb = (g < 2) ? Wbot : Wd;
  int lane = tid & 63, wv = tid >> 6;
  int m16 = lane & 15, quad = lane >> 4;
  int sr = tid >> 3, sseg = tid & 7;

  floatx4 acc[8];
#pragma unroll
  for (int nt = 0; nt < 8; ++nt) acc[nt] = (floatx4){0.f, 0.f, 0.f, 0.f};

  for (int kb = 0; kb < K; kb += 64) {
    __syncthreads();
#pragma unroll
    for (int i = 0; i < 2; ++i) {
      int r = sr + i * 32;
      *(int4*)&A_lds[r * 72 + sseg * 8] =
          *(const int4*)(A + (size_t)(row0 + r) * K + kb + sseg * 8);
    }
#pragma unroll
    for (int i = 0; i < 4; ++i) {
      int r = sr + i * 32;
      *(int4*)&B_lds[r * 72 + sseg * 8] =
          *(const int4*)(Wb + (size_t)(col0 + r) * K + kb + sseg * 8);
    }
    __syncthreads();
#pragma unroll
    for (int ks = 0; ks < 2; ++ks) {
      bhalf8 a = *(const bhalf8*)&A_lds[(wv * 16 + m16) * 72 + ks * 32 + quad * 8];
#pragma unroll
      for (int nt = 0; nt < 8; ++nt) {
        bhalf8 b = *(const bhalf8*)&B_lds[(nt * 16 + m16) * 72 + ks * 32 + quad * 8];
        acc[nt] = __builtin_amdgcn_mfma_f32_16x16x32_bf16(a, b, acc[nt], 0, 0, 0);
      }
    }
  }

  int g0 = row0 + wv * 16 + quad * 4;
  if (g < 2) {
#pragma unroll
    for (int nt = 0; nt < 8; ++nt) {
      int c = col0 + nt * 16 + m16;
#pragma unroll
      for (int r = 0; r < 4; ++r)
        Bm[(size_t)(g0 + r) * 256 + c] = f2bf(acc[nt][r]);
    }
  } else {
#pragma unroll
    for (int nt = 0; nt < 8; ++nt) {
      int c = col0 + nt * 16 + m16;
      float bv = bias[c];
#pragma unroll
      for (int r = 0; r < 4; ++r)
        P[(size_t)(g0 + r) * 256 + c] = f2bf(acc[nt][r] + bv);
    }
  }
}

// ---------------- segment max + fused relu epilogue ----------------
// per node: M = max over in-edge sources of Bm rows (-inf if empty),
// X1 = relu(P + M)  (empty -> relu(-inf) = 0, matching PyG fill)
__global__ __launch_bounds__(256) void k_maxg2(const unsigned short* __restrict__ Bm,
                                               const int* __restrict__ cnt,
                                               const int* __restrict__ slot,
                                               const unsigned short* __restrict__ P,
                                               unsigned short* __restrict__ X1) {
  int node = blockIdx.x * 4 + (threadIdx.x >> 6);
  int lane = threadIdx.x & 63;
  int n = cnt[node];
  if (n > CAP) n = CAP;
  const int* sl = slot + (size_t)node * CAP;
  float4 m = make_float4(-INFINITY, -INFINITY, -INFINITY, -INFINITY);
  int i = 0;
  for (; i + 4 <= n; i += 4) {
    int s0 = sl[i], s1 = sl[i + 1], s2 = sl[i + 2], s3 = sl[i + 3];
    ushort4 v0 = *(const ushort4*)(Bm + (size_t)s0 * 256 + lane * 4);
    ushort4 v1 = *(const ushort4*)(Bm + (size_t)s1 * 256 + lane * 4);
    ushort4 v2 = *(const ushort4*)(Bm + (size_t)s2 * 256 + lane * 4);
    ushort4 v3 = *(const ushort4*)(Bm + (size_t)s3 * 256 + lane * 4);
    m.x = fmaxf(fmaxf(fmaxf(m.x, bf2f(v0.x)), fmaxf(bf2f(v1.x), bf2f(v2.x))), bf2f(v3.x));
    m.y = fmaxf(fmaxf(fmaxf(m.y, bf2f(v0.y)), fmaxf(bf2f(v1.y), bf2f(v2.y))), bf2f(v3.y));
    m.z = fmaxf(fmaxf(fmaxf(m.z, bf2f(v0.z)), fmaxf(bf2f(v1.z), bf2f(v2.z))), bf2f(v3.z));
    m.w = fmaxf(fmaxf(fmaxf(m.w, bf2f(v0.w)), fmaxf(bf2f(v1.w), bf2f(v2.w))), bf2f(v3.w));
  }
  for (; i < n; ++i) {
    int s = sl[i];
    ushort4 v = *(const ushort4*)(Bm + (size_t)s * 256 + lane * 4);
    m.x = fmaxf(m.x, bf2f(v.x));
    m.y = fmaxf(m.y, bf2f(v.y));
    m.z = fmaxf(m.z, bf2f(v.z));
    m.w = fmaxf(m.w, bf2f(v.w));
  }
  ushort4 p = *(const ushort4*)(P + (size_t)node * 256 + lane * 4);
  ushort4 o;
  o.x = f2bf(fmaxf(bf2f(p.x) + m.x, 0.f));
  o.y = f2bf(fmaxf(bf2f(p.y) + m.y, 0.f));
  o.z = f2bf(fmaxf(bf2f(p.z) + m.z, 0.f));
  o.w = f2bf(fmaxf(bf2f(p.w) + m.w, 0.f));
  *(ushort4*)(X1 + (size_t)node * 256 + lane * 4) = o;
}

// ---------------- MFMA temporal conv: 32x32x16, all taps staged ----------------
// Y = maxpool2(relu(conv1d(X, Wtb, k=5, pad=2) + bc)); X bf16 [M][256] as [BN][TRows][256]
// Block: 128 rows x (NT*64) cols, 4 waves. Wave w: row half h=(w&1) (2 row-tiles of 32),
// col part c=(w>>1) (NT col-tiles of 32). Per K-chunk of 32: stage 2 halo windows of A
// + all 5 taps of B, then MFMAs entirely out of LDS.
// C/D layout (32x32): col=lane&31, row=(reg&3)+8*(reg>>2)+4*(lane>>5); pool pairs are
// adjacent regs in the same lane.
template <int TRows, int NT, bool OUT_F32>
__global__ __launch_bounds__(256) void k_conv32(const unsigned short* __restrict__ X,
                                                const unsigned short* __restrict__ Wtb,
                                                const float* __restrict__ bc,
                                                void* __restrict__ Yout) {
  const int CB = NT * 64;                        // block cols
  __shared__ __align__(16) short A_lds[2 * 68 * 40];   // [win][row 0..67][k32 + pad8]
  __shared__ __align__(16) short B_lds[5 * CB * 40];   // [tap*CB + col][k32 + pad8]
  int tid = threadIdx.x;
  int row0 = blockIdx.x * 128;
  int col0 = blockIdx.y * CB;
  int lane = tid & 63, wv = tid >> 6;
  int l31 = lane & 31, khalf = lane >> 5;
  int h = wv & 1, cpart = wv >> 1;

  floatx16 acc[2][NT];
#pragma unroll
  for (int rt = 0; rt < 2; ++rt)
#pragma unroll
    for (int ct = 0; ct < NT; ++ct)
#pragma unroll
      for (int r = 0; r < 16; ++r) acc[rt][ct][r] = 0.f;

  for (int kb = 0; kb < 256; kb += 32) {
    __syncthreads();
    // stage A: two 68-row halo windows (rows base-2 .. base+66), zero outside bn
    for (int u = tid; u < 544; u += 256) {
      int s = (u >= 272) ? 1 : 0;
      int v = u - s * 272;
      int rr = v >> 2, seg = v & 3;
      int base = row0 + s * 64;
      int lo = base & ~(TRows - 1);
      int gr = base + rr - 2;
      int4 val = {0, 0, 0, 0};
      if (gr >= lo && gr < lo + TRows)
        val = *(const int4*)(X + (size_t)gr * 256 + kb + seg * 8);
      *(int4*)&A_lds[(s * 68 + rr) * 40 + seg * 8] = val;
    }
    // stage B: 5 taps x CB cols x 32 k
#pragma unroll
    for (int i = 0; i < 5 * NT; ++i) {
      int u = tid + i * 256;            // 5*CB rows x 4 segs
      int r = u >> 2, seg = u & 3;      // r = tap*CB + col
      int tap = r / CB, col = r % CB;
      *(int4*)&B_lds[r * 40 + seg * 8] =
          *(const int4*)(Wtb + (size_t)tap * 65536 + (size_t)(col0 + col) * 256 + kb + seg * 8);
    }
    __syncthreads();
#pragma unroll
    for (int tap = 0; tap < 5; ++tap) {
#pragma unroll
      for (int ks = 0; ks < 2; ++ks) {
        int ko = ks * 16 + khalf * 8;
        bhalf8 a[2];
#pragma unroll
        for (int rt = 0; rt < 2; ++rt)
          a[rt] = *(const bhalf8*)&A_lds[(h * 68 + rt * 32 + l31 + tap) * 40 + ko];
#pragma unroll
        for (int ct = 0; ct < NT; ++ct) {
          bhalf8 b = *(const bhalf8*)&B_lds[(tap * CB + cpart * NT * 32 + ct * 32 + l31) * 40 + ko];
#pragma unroll
          for (int rt = 0; rt < 2; ++rt)
            acc[rt][ct] = __builtin_amdgcn_mfma_f32_32x32x16_bf16(a[rt], b, acc[rt][ct], 0, 0, 0);
        }
      }
    }
  }

#pragma unroll
  for (int rt = 0; rt < 2; ++rt) {
#pragma unroll
    for (int ct = 0; ct < NT; ++ct) {
      int c = col0 + cpart * NT * 32 + ct * 32 + l31;
      float bv = bc[c];
#pragma unroll
      for (int r = 0; r < 16; r += 2) {
        int rowg = row0 + h * 64 + rt * 32 + 4 * khalf + 8 * (r >> 2) + (r & 3);
        float y0 = fmaxf(acc[rt][ct][r] + bv, 0.f);
        float y1 = fmaxf(acc[rt][ct][r + 1] + bv, 0.f);
        float p = fmaxf(y0, y1);
        int o = rowg >> 1;
        if (OUT_F32) ((float*)Yout)[(size_t)o * 256 + c] = p;
        else ((unsigned short*)Yout)[(size_t)o * 256 + c] = f2bf(p);
      }
    }
  }
}

extern "C" void kernel_launch(void* const* d_in, const int* in_sizes, int n_in,
                              void* d_out, int out_size, void* d_ws, size_t ws_size,
                              hipStream_t stream) {
  const float* data = (const float*)d_in[0];
  const int* ei0 = (const int*)d_in[2];
  const int* ei1 = (const int*)d_in[3];
  const float* W0  = (const float*)d_in[4];
  const float* b0  = (const float*)d_in[5];
  const float* Wc0 = (const float*)d_in[6];
  const float* bc0 = (const float*)d_in[7];
  const float* W1  = (const float*)d_in[8];
  const float* b1  = (const float*)d_in[9];
  const float* Wc1 = (const float*)d_in[10];
  const float* bc1 = (const float*)d_in[11];
  float* out = (float*)d_out;

  char* base = (char*)d_ws;
  size_t off = 0;
  auto alloc = [&](size_t bytes) { void* p = base + off; off += (bytes + 255) & ~(size_t)255; return p; };
  unsigned short* X0b   = (unsigned short*)alloc((size_t)NODE0 * Ff * 2);
  unsigned short* Bm    = (unsigned short*)alloc((size_t)NODE0 * Hh * 2);
  unsigned short* P     = (unsigned short*)alloc((size_t)NODE0 * Hh * 2);
  unsigned short* X1b   = (unsigned short*)alloc((size_t)NODE0 * Hh * 2);
  unsigned short* Y0b   = (unsigned short*)alloc((size_t)NODE1 * Hh * 2);
  unsigned short* Wbot0 = (unsigned short*)alloc(256 * 128 * 2);
  unsigned short* Wd0   = (unsigned short*)alloc(256 * 128 * 2);
  unsigned short* Wbot1 = (unsigned short*)alloc(256 * 256 * 2);
  unsigned short* Wd1   = (unsigned short*)alloc(256 * 256 * 2);
  unsigned short* Wtb0  = (unsigned short*)alloc(5 * 65536 * 2);
  unsigned short* Wtb1  = (unsigned short*)alloc(5 * 65536 * 2);
  int* cnt0  = (int*)alloc(NODE0 * 4);      // cnt0+cnt1 adjacent: one memset
  int* cnt1  = (int*)alloc(NODE1 * 4);
  int* slot0 = (int*)alloc((size_t)NODE0 * CAP * 4);
  int* slot1 = (int*)alloc((size_t)NODE1 * CAP * 4);

  hipMemsetAsync(cnt0, 0, (NODE0 + NODE1) * sizeof(int), stream);

  k_prepfill<<<6528, 256, 0, stream>>>(data, X0b, W0, Wbot0, Wd0, W1, Wbot1, Wd1,
                                       Wc0, Wtb0, Wc1, Wtb1,
                                       ei0, ei1, cnt0, cnt1, slot0, slot1);

  // ---- layer 0 ----
  k_gemm2<<<dim3(NODE0 / 64, 4), 256, 0, stream>>>(X0b, Wbot0, Wd0, Bm, P, 128, b0);
  k_maxg2<<<NODE0 / 4, 256, 0, stream>>>(Bm, cnt0, slot0, P, X1b);
  k_conv32<128, 1, false><<<dim3(NODE0 / 128, 4), 256, 0, stream>>>(X1b, Wtb0, bc0, Y0b);

  // ---- layer 1 ----
  k_gemm2<<<dim3(NODE1 / 64, 4), 256, 0, stream>>>(Y0b, Wbot1, Wd1, Bm, P, 256, b1);
  k_maxg2<<<NODE1 / 4, 256, 0, stream>>>(Bm, cnt1, slot1, P, X1b);
  k_conv32<64, 1, true><<<dim3(NODE1 / 128, 4), 256, 0, stream>>>(X1b, Wtb1, bc1, out);
}

// Round 10
// 213.119 us; speedup vs baseline: 1.5901x; 1.0503x over previous
//
#include <hip/hip_runtime.h>
#include <hip/hip_bf16.h>
#include <math.h>

#define T0 128
#define BN 256           // B*N = 8*32
#define Ff 128
#define Hh 256
#define NODE0 32768      // BN*T0
#define E0 262144        // NODE0*8
#define T1 64
#define NODE1 16384      // BN*T1
#define E1 131072
#define CAP 48           // per-node in-edge capacity; deg ~ Poisson(8), P(>48) ~ 1e-25

typedef __attribute__((ext_vector_type(8))) short bhalf8;
typedef __attribute__((ext_vector_type(4))) float floatx4;
typedef __attribute__((ext_vector_type(16))) float floatx16;

__device__ __forceinline__ unsigned short f2bf(float x) {
  union { float f; unsigned u; } v; v.f = x;
  unsigned r = v.u + 0x7fff + ((v.u >> 16) & 1);
  return (unsigned short)(r >> 16);
}
__device__ __forceinline__ float bf2f(unsigned short b) {
  union { unsigned u; float f; } v; v.u = ((unsigned)b) << 16;
  return v.f;
}

// ---------------- fused prep + edge-fill kernel ----------------
// blocks [0,2048): data fp32 [T][BN][F] -> X0b bf16 [bn*T+t][F]
// [2048,2176): W0 -> Wbot0/Wd0 ; [2176,2432): W1 -> Wbot1/Wd1
// [2432,3712): Wc0 -> Wtb0 ; [3712,4992): Wc1 -> Wtb1
// [4992,6528): bucketed edge fill for both layers
__global__ void k_prepfill(const float* __restrict__ data, unsigned short* __restrict__ X0b,
                           const float* __restrict__ W0, unsigned short* __restrict__ Wbot0,
                           unsigned short* __restrict__ Wd0,
                           const float* __restrict__ W1, unsigned short* __restrict__ Wbot1,
                           unsigned short* __restrict__ Wd1,
                           const float* __restrict__ Wc0, unsigned short* __restrict__ Wtb0,
                           const float* __restrict__ Wc1, unsigned short* __restrict__ Wtb1,
                           const int* __restrict__ ei0, const int* __restrict__ ei1,
                           int* __restrict__ cnt0, int* __restrict__ cnt1,
                           int* __restrict__ slot0, int* __restrict__ slot1) {
  int b = blockIdx.x;
  int tid = threadIdx.x;
  if (b < 2048) {
    int idx = b * 256 + tid;          // NODE0*16, 8 elems each
    int c8 = idx & 15;
    int r  = idx >> 4;
    int t  = r & (T0 - 1);
    int bn = r >> 7;
    const float* s = data + ((size_t)t * BN + bn) * Ff + c8 * 8;
    float4 a = *(const float4*)s;
    float4 bb = *(const float4*)(s + 4);
    unsigned short o[8];
    o[0] = f2bf(a.x); o[1] = f2bf(a.y); o[2] = f2bf(a.z); o[3] = f2bf(a.w);
    o[4] = f2bf(bb.x); o[5] = f2bf(bb.y); o[6] = f2bf(bb.z); o[7] = f2bf(bb.w);
    *(int4*)(X0b + ((size_t)(bn * T0 + t) * Ff + c8 * 8)) = *(int4*)o;
  } else if (b < 2176) {
    int idx = (b - 2048) * 256 + tid; // 32768 = 256*128
    int n = idx >> 7, k = idx & 127;
    float top = W0[(size_t)k * 256 + n];
    float bot = W0[(size_t)(128 + k) * 256 + n];
    Wbot0[idx] = f2bf(bot);
    Wd0[idx]   = f2bf(top - bot);
  } else if (b < 2432) {
    int idx = (b - 2176) * 256 + tid; // 65536 = 256*256
    int n = idx >> 8, k = idx & 255;
    float top = W1[(size_t)k * 256 + n];
    float bot = W1[(size_t)(256 + k) * 256 + n];
    Wbot1[idx] = f2bf(bot);
    Wd1[idx]   = f2bf(top - bot);
  } else if (b < 3712) {
    int idx = (b - 2432) * 256 + tid; // 5*65536
    int tap = idx >> 16, o = (idx >> 8) & 255, i = idx & 255;
    Wtb0[idx] = f2bf(Wc0[((size_t)o * 256 + i) * 5 + tap]);
  } else if (b < 4992) {
    int idx = (b - 3712) * 256 + tid;
    int tap = idx >> 16, o = (idx >> 8) & 255, i = idx & 255;
    Wtb1[idx] = f2bf(Wc1[((size_t)o * 256 + i) * 5 + tap]);
  } else {
    int e = (b - 4992) * 256 + tid;   // E0+E1 = 393216 over 1536 blocks
    if (e < E0) {
      int d = ei0[E0 + e];
      int p = atomicAdd(&cnt0[d], 1);
      if (p < CAP) slot0[(size_t)d * CAP + p] = ei0[e];
    } else {
      int e2 = e - E0;
      int d = ei1[E1 + e2];
      int p = atomicAdd(&cnt1[d], 1);
      if (p < CAP) slot1[(size_t)d * CAP + p] = ei1[e2];
    }
  }
}

// ---------------- fused dual-output MFMA GEMM ----------------
// One block: 64 rows x 128 cols, computing BOTH Bm = A@Wbot (bf16)
// and P = A@Wd + bias (bf16). A staged once per kb; Wbot/Wd in two LDS buffers.
__global__ __launch_bounds__(256) void k_gemm2(const unsigned short* __restrict__ A,
                                               const unsigned short* __restrict__ Wbot,
                                               const unsigned short* __restrict__ Wd,
                                               unsigned short* __restrict__ Bm,
                                               unsigned short* __restrict__ P, int K,
                                               const float* __restrict__ bias) {
  __shared__ __align__(16) short A_lds[64 * 72];
  __shared__ __align__(16) short B0_lds[128 * 72];
  __shared__ __align__(16) short B1_lds[128 * 72];
  int tid = threadIdx.x;
  int row0 = blockIdx.x * 64;
  int col0 = blockIdx.y * 128;
  int lane = tid & 63, wv = tid >> 6;
  int m16 = lane & 15, quad = lane >> 4;
  int sr = tid >> 3, sseg = tid & 7;

  floatx4 accB[8], accP[8];
#pragma unroll
  for (int nt = 0; nt < 8; ++nt) {
    accB[nt] = (floatx4){0.f, 0.f, 0.f, 0.f};
    accP[nt] = (floatx4){0.f, 0.f, 0.f, 0.f};
  }

  for (int kb = 0; kb < K; kb += 64) {
    __syncthreads();
#pragma unroll
    for (int i = 0; i < 2; ++i) {
      int r = sr + i * 32;
      *(int4*)&A_lds[r * 72 + sseg * 8] =
          *(const int4*)(A + (size_t)(row0 + r) * K + kb + sseg * 8);
    }
#pragma unroll
    for (int i = 0; i < 4; ++i) {
      int r = sr + i * 32;
      *(int4*)&B0_lds[r * 72 + sseg * 8] =
          *(const int4*)(Wbot + (size_t)(col0 + r) * K + kb + sseg * 8);
      *(int4*)&B1_lds[r * 72 + sseg * 8] =
          *(const int4*)(Wd + (size_t)(col0 + r) * K + kb + sseg * 8);
    }
    __syncthreads();
#pragma unroll
    for (int ks = 0; ks < 2; ++ks) {
      bhalf8 a = *(const bhalf8*)&A_lds[(wv * 16 + m16) * 72 + ks * 32 + quad * 8];
#pragma unroll
      for (int nt = 0; nt < 8; ++nt) {
        bhalf8 b0 = *(const bhalf8*)&B0_lds[(nt * 16 + m16) * 72 + ks * 32 + quad * 8];
        accB[nt] = __builtin_amdgcn_mfma_f32_16x16x32_bf16(a, b0, accB[nt], 0, 0, 0);
        bhalf8 b1 = *(const bhalf8*)&B1_lds[(nt * 16 + m16) * 72 + ks * 32 + quad * 8];
        accP[nt] = __builtin_amdgcn_mfma_f32_16x16x32_bf16(a, b1, accP[nt], 0, 0, 0);
      }
    }
  }

  int g0 = row0 + wv * 16 + quad * 4;
#pragma unroll
  for (int nt = 0; nt < 8; ++nt) {
    int c = col0 + nt * 16 + m16;
    float bv = bias[c];
#pragma unroll
    for (int r = 0; r < 4; ++r) {
      Bm[(size_t)(g0 + r) * 256 + c] = f2bf(accB[nt][r]);
      P[(size_t)(g0 + r) * 256 + c]  = f2bf(accP[nt][r] + bv);
    }
  }
}

// ---------------- segment max + fused relu epilogue ----------------
// per node: M = max over in-edge sources of Bm rows (-inf if empty),
// X1 = relu(P + M)  (empty -> relu(-inf) = 0, matching PyG fill).
// Gather issues 8 concurrent predicated row loads per pass (index clamped to
// n-1; duplicate maxes are idempotent) to keep 8 LLC fetches in flight.
__global__ __launch_bounds__(256) void k_maxg2(const unsigned short* __restrict__ Bm,
                                               const int* __restrict__ cnt,
                                               const int* __restrict__ slot,
                                               const unsigned short* __restrict__ P,
                                               unsigned short* __restrict__ X1) {
  int node = blockIdx.x * 4 + (threadIdx.x >> 6);
  int lane = threadIdx.x & 63;
  int n = cnt[node];
  if (n > CAP) n = CAP;
  const int* sl = slot + (size_t)node * CAP;
  float4 m = make_float4(-INFINITY, -INFINITY, -INFINITY, -INFINITY);
  for (int i = 0; i < n; i += 8) {
    int s[8];
#pragma unroll
    for (int j = 0; j < 8; ++j) {
      int idx = i + j;
      s[j] = sl[(idx < n) ? idx : (n - 1)];
    }
    ushort4 v[8];
#pragma unroll
    for (int j = 0; j < 8; ++j)
      v[j] = *(const ushort4*)(Bm + (size_t)s[j] * 256 + lane * 4);
#pragma unroll
    for (int j = 0; j < 8; ++j) {
      m.x = fmaxf(m.x, bf2f(v[j].x));
      m.y = fmaxf(m.y, bf2f(v[j].y));
      m.z = fmaxf(m.z, bf2f(v[j].z));
      m.w = fmaxf(m.w, bf2f(v[j].w));
    }
  }
  ushort4 p = *(const ushort4*)(P + (size_t)node * 256 + lane * 4);
  ushort4 o;
  o.x = f2bf(fmaxf(bf2f(p.x) + m.x, 0.f));
  o.y = f2bf(fmaxf(bf2f(p.y) + m.y, 0.f));
  o.z = f2bf(fmaxf(bf2f(p.z) + m.z, 0.f));
  o.w = f2bf(fmaxf(bf2f(p.w) + m.w, 0.f));
  *(ushort4*)(X1 + (size_t)node * 256 + lane * 4) = o;
}

// ---------------- MFMA temporal conv: 32x32x16, all taps staged ----------------
// Y = maxpool2(relu(conv1d(X, Wtb, k=5, pad=2) + bc)); X bf16 [M][256] as [BN][TRows][256]
// Block: 128 rows x (NT*64) cols, 4 waves. Wave w: row half h=(w&1) (2 row-tiles of 32),
// col part c=(w>>1) (NT col-tiles of 32). Per K-chunk of 32: stage 2 halo windows of A
// + all 5 taps of B, then MFMAs entirely out of LDS.
// C/D layout (32x32): col=lane&31, row=(reg&3)+8*(reg>>2)+4*(lane>>5); pool pairs are
// adjacent regs in the same lane.
template <int TRows, int NT, bool OUT_F32>
__global__ __launch_bounds__(256) void k_conv32(const unsigned short* __restrict__ X,
                                                const unsigned short* __restrict__ Wtb,
                                                const float* __restrict__ bc,
                                                void* __restrict__ Yout) {
  const int CB = NT * 64;                        // block cols
  __shared__ __align__(16) short A_lds[2 * 68 * 40];   // [win][row 0..67][k32 + pad8]
  __shared__ __align__(16) short B_lds[5 * CB * 40];   // [tap*CB + col][k32 + pad8]
  int tid = threadIdx.x;
  int row0 = blockIdx.x * 128;
  int col0 = blockIdx.y * CB;
  int lane = tid & 63, wv = tid >> 6;
  int l31 = lane & 31, khalf = lane >> 5;
  int h = wv & 1, cpart = wv >> 1;

  floatx16 acc[2][NT];
#pragma unroll
  for (int rt = 0; rt < 2; ++rt)
#pragma unroll
    for (int ct = 0; ct < NT; ++ct)
#pragma unroll
      for (int r = 0; r < 16; ++r) acc[rt][ct][r] = 0.f;

  for (int kb = 0; kb < 256; kb += 32) {
    __syncthreads();
    // stage A: two 68-row halo windows (rows base-2 .. base+66), zero outside bn
    for (int u = tid; u < 544; u += 256) {
      int s = (u >= 272) ? 1 : 0;
      int v = u - s * 272;
      int rr = v >> 2, seg = v & 3;
      int base = row0 + s * 64;
      int lo = base & ~(TRows - 1);
      int gr = base + rr - 2;
      int4 val = {0, 0, 0, 0};
      if (gr >= lo && gr < lo + TRows)
        val = *(const int4*)(X + (size_t)gr * 256 + kb + seg * 8);
      *(int4*)&A_lds[(s * 68 + rr) * 40 + seg * 8] = val;
    }
    // stage B: 5 taps x CB cols x 32 k
#pragma unroll
    for (int i = 0; i < 5 * NT; ++i) {
      int u = tid + i * 256;            // 5*CB rows x 4 segs
      int r = u >> 2, seg = u & 3;      // r = tap*CB + col
      int tap = r / CB, col = r % CB;
      *(int4*)&B_lds[r * 40 + seg * 8] =
          *(const int4*)(Wtb + (size_t)tap * 65536 + (size_t)(col0 + col) * 256 + kb + seg * 8);
    }
    __syncthreads();
#pragma unroll
    for (int tap = 0; tap < 5; ++tap) {
#pragma unroll
      for (int ks = 0; ks < 2; ++ks) {
        int ko = ks * 16 + khalf * 8;
        bhalf8 a[2];
#pragma unroll
        for (int rt = 0; rt < 2; ++rt)
          a[rt] = *(const bhalf8*)&A_lds[(h * 68 + rt * 32 + l31 + tap) * 40 + ko];
#pragma unroll
        for (int ct = 0; ct < NT; ++ct) {
          bhalf8 b = *(const bhalf8*)&B_lds[(tap * CB + cpart * NT * 32 + ct * 32 + l31) * 40 + ko];
#pragma unroll
          for (int rt = 0; rt < 2; ++rt)
            acc[rt][ct] = __builtin_amdgcn_mfma_f32_32x32x16_bf16(a[rt], b, acc[rt][ct], 0, 0, 0);
        }
      }
    }
  }

#pragma unroll
  for (int rt = 0; rt < 2; ++rt) {
#pragma unroll
    for (int ct = 0; ct < NT; ++ct) {
      int c = col0 + cpart * NT * 32 + ct * 32 + l31;
      float bv = bc[c];
#pragma unroll
      for (int r = 0; r < 16; r += 2) {
        int rowg = row0 + h * 64 + rt * 32 + 4 * khalf + 8 * (r >> 2) + (r & 3);
        float y0 = fmaxf(acc[rt][ct][r] + bv, 0.f);
        float y1 = fmaxf(acc[rt][ct][r + 1] + bv, 0.f);
        float p = fmaxf(y0, y1);
        int o = rowg >> 1;
        if (OUT_F32) ((float*)Yout)[(size_t)o * 256 + c] = p;
        else ((unsigned short*)Yout)[(size_t)o * 256 + c] = f2bf(p);
      }
    }
  }
}

extern "C" void kernel_launch(void* const* d_in, const int* in_sizes, int n_in,
                              void* d_out, int out_size, void* d_ws, size_t ws_size,
                              hipStream_t stream) {
  const float* data = (const float*)d_in[0];
  const int* ei0 = (const int*)d_in[2];
  const int* ei1 = (const int*)d_in[3];
  const float* W0  = (const float*)d_in[4];
  const float* b0  = (const float*)d_in[5];
  const float* Wc0 = (const float*)d_in[6];
  const float* bc0 = (const float*)d_in[7];
  const float* W1  = (const float*)d_in[8];
  const float* b1  = (const float*)d_in[9];
  const float* Wc1 = (const float*)d_in[10];
  const float* bc1 = (const float*)d_in[11];
  float* out = (float*)d_out;

  char* base = (char*)d_ws;
  size_t off = 0;
  auto alloc = [&](size_t bytes) { void* p = base + off; off += (bytes + 255) & ~(size_t)255; return p; };
  unsigned short* X0b   = (unsigned short*)alloc((size_t)NODE0 * Ff * 2);
  unsigned short* Bm    = (unsigned short*)alloc((size_t)NODE0 * Hh * 2);
  unsigned short* P     = (unsigned short*)alloc((size_t)NODE0 * Hh * 2);
  unsigned short* X1b   = (unsigned short*)alloc((size_t)NODE0 * Hh * 2);
  unsigned short* Y0b   = (unsigned short*)alloc((size_t)NODE1 * Hh * 2);
  unsigned short* Wbot0 = (unsigned short*)alloc(256 * 128 * 2);
  unsigned short* Wd0   = (unsigned short*)alloc(256 * 128 * 2);
  unsigned short* Wbot1 = (unsigned short*)alloc(256 * 256 * 2);
  unsigned short* Wd1   = (unsigned short*)alloc(256 * 256 * 2);
  unsigned short* Wtb0  = (unsigned short*)alloc(5 * 65536 * 2);
  unsigned short* Wtb1  = (unsigned short*)alloc(5 * 65536 * 2);
  int* cnt0  = (int*)alloc(NODE0 * 4);      // cnt0+cnt1 adjacent: one memset
  int* cnt1  = (int*)alloc(NODE1 * 4);
  int* slot0 = (int*)alloc((size_t)NODE0 * CAP * 4);
  int* slot1 = (int*)alloc((size_t)NODE1 * CAP * 4);

  hipMemsetAsync(cnt0, 0, (NODE0 + NODE1) * sizeof(int), stream);

  k_prepfill<<<6528, 256, 0, stream>>>(data, X0b, W0, Wbot0, Wd0, W1, Wbot1, Wd1,
                                       Wc0, Wtb0, Wc1, Wtb1,
                                       ei0, ei1, cnt0, cnt1, slot0, slot1);

  // ---- layer 0 ----
  k_gemm2<<<dim3(NODE0 / 64, 2), 256, 0, stream>>>(X0b, Wbot0, Wd0, Bm, P, 128, b0);
  k_maxg2<<<NODE0 / 4, 256, 0, stream>>>(Bm, cnt0, slot0, P, X1b);
  k_conv32<128, 1, false><<<dim3(NODE0 / 128, 4), 256, 0, stream>>>(X1b, Wtb0, bc0, Y0b);

  // ---- layer 1 ----
  k_gemm2<<<dim3(NODE1 / 64, 2), 256, 0, stream>>>(Y0b, Wbot1, Wd1, Bm, P, 256, b1);
  k_maxg2<<<NODE1 / 4, 256, 0, stream>>>(Bm, cnt1, slot1, P, X1b);
  k_conv32<64, 1, true><<<dim3(NODE1 / 128, 4), 256, 0, stream>>>(X1b, Wtb1, bc1, out);
}